// Round 4
// baseline (548.498 us; speedup 1.0000x reference)
//
#include <hip/hip_runtime.h>
#include <math.h>

typedef float v2f __attribute__((ext_vector_type(2)));

constexpr int KW      = 56;
constexpr int NB      = 1792;
constexpr int QKV_CH  = 128;
constexpr int SIM_CH  = 24;
constexpr float EPS   = 1e-5f;

constexpr int   PA[10]  = {0,0,0,0,1,1,1,2,2,3};
constexpr int   PB[10]  = {0,1,2,3,1,2,3,2,3,3};
constexpr float PMf[10] = {1,2,2,2,1,2,2,1,2,1};

// ---------------- setup: rel-derived tables for sim stats ----------------
__global__ void k_setup(const float* __restrict__ rel, float* __restrict__ tabs) {
    const int t = threadIdx.x;
    float* Rq  = tabs;
    float* Rk  = tabs + 224;
    float* E2q = tabs + 448;
    float* E2k = tabs + 1008;
    for (int idx = t; idx < 448; idx += 256) {
        int which = idx / 224, r = idx % 224;
        int i = r >> 2, c = r & 3;
        const float* src = rel + (which * 4 + c) * 111;
        float s = 0.f;
        for (int tt = 0; tt < 56; ++tt) s += src[i + tt];
        (which ? Rk : Rq)[r] = s;
    }
    for (int idx = t; idx < 1120; idx += 256) {
        int which = idx / 560, r = idx % 560;
        int i = r / 10, p = r % 10;
        const float* sa = rel + (which * 4 + PA[p]) * 111;
        const float* sb = rel + (which * 4 + PB[p]) * 111;
        float s = 0.f;
        for (int tt = 0; tt < 56; ++tt) s += sa[i + tt] * sb[i + tt];
        (which ? E2k : E2q)[r] = s;
    }
}

// ---------------- fold: per-g {lo,delta} attention tables (needs sim_coef) ---
// WQK[g][s][16]: [ {loq0,dq0,..,loq3,dq3} * 0.1*aqr_g | {klo0..3, khi0..3} * 0.1*akr_g ]
// WV[s][16]:     { lov0, dv0, ..., lov7, dv7 }   (raw rel rows 8..15)
__global__ void k_fold(const float* __restrict__ rel, const float* __restrict__ scoef,
                       float* __restrict__ WQK, float* __restrict__ WV) {
    const int t = threadIdx.x;
    for (int idx = t; idx < 448; idx += 256) {
        int g = idx / 56, s = idx % 56;
        float aqr = scoef[8 + g] * 0.1f;
        float akr = scoef[16 + g] * 0.1f;
        float* W = WQK + (g * 56 + s) * 16;
#pragma unroll
        for (int c = 0; c < 4; ++c) {
            float lo = rel[c * 111 + 55 - s];
            float hi = (s > 0) ? rel[c * 111 + 111 - s] : lo;
            W[c * 2]     = aqr * lo;
            W[c * 2 + 1] = aqr * (hi - lo);
            float klo = rel[(4 + c) * 111 + 55 + s];
            float khi = (s > 0) ? rel[(4 + c) * 111 + s - 1] : 0.f;
            W[8 + c]  = akr * klo;
            W[12 + c] = akr * khi;
        }
    }
    for (int s = t; s < 56; s += 256) {
        float* V = WV + s * 16;
#pragma unroll
        for (int c = 0; c < 8; ++c) {
            float lo = rel[(8 + c) * 111 + 55 - s];
            float hi = (s > 0) ? rel[(8 + c) * 111 + 111 - s] : lo;
            V[c * 2]     = lo;
            V[c * 2 + 1] = hi - lo;
        }
    }
}

// ---------------- Kernel A: qkv[b][i][o] = w @ x + per-channel stats ----------
__global__ __launch_bounds__(256) void k_qkv(const float* __restrict__ x,
                                             const float* __restrict__ w,
                                             float* __restrict__ qkv,
                                             float* __restrict__ sums) {
    __shared__ float xs[64 * KW];
    __shared__ float wt[64 * 128];
    __shared__ float s1[128], s2[128];
    const int b = blockIdx.x, t = threadIdx.x;

    if (t < 128) { s1[t] = 0.f; s2[t] = 0.f; }
    for (int idx = t; idx < 896; idx += 256) {
        int c = idx / 14, r = idx % 14;
        float4 v = *(const float4*)&x[c * 100352 + b * 56 + r * 4];
        *(float4*)&xs[c * 56 + r * 4] = v;
    }
    for (int idx = t; idx < 2048; idx += 256) {
        int o = idx >> 4, cq = idx & 15;
        float4 v = *(const float4*)&w[o * 64 + cq * 4];
        wt[(cq * 4 + 0) * 128 + o] = v.x;
        wt[(cq * 4 + 1) * 128 + o] = v.y;
        wt[(cq * 4 + 2) * 128 + o] = v.z;
        wt[(cq * 4 + 3) * 128 + o] = v.w;
    }
    __syncthreads();

    if (t < 224) {
        const int ob = t & 31, ib = t >> 5;
        v2f acc[4][4];   // [o][ipair]
#pragma unroll
        for (int o = 0; o < 4; ++o)
#pragma unroll
            for (int ip = 0; ip < 4; ++ip) acc[o][ip] = (v2f)(0.f);
        for (int c = 0; c < 64; ++c) {
            float4 wv = *(const float4*)&wt[c * 128 + (ob << 2)];
            float4 x0 = *(const float4*)&xs[c * 56 + (ib << 3)];
            float4 x1 = *(const float4*)&xs[c * 56 + (ib << 3) + 4];
            v2f xp[4];
            xp[0] = (v2f){x0.x, x0.y}; xp[1] = (v2f){x0.z, x0.w};
            xp[2] = (v2f){x1.x, x1.y}; xp[3] = (v2f){x1.z, x1.w};
            v2f wd[4];
            wd[0] = (v2f)(wv.x); wd[1] = (v2f)(wv.y);
            wd[2] = (v2f)(wv.z); wd[3] = (v2f)(wv.w);
#pragma unroll
            for (int o = 0; o < 4; ++o)
#pragma unroll
                for (int ip = 0; ip < 4; ++ip)
                    acc[o][ip] += wd[o] * xp[ip];
        }
#pragma unroll
        for (int i = 0; i < 8; ++i) {
            float4 st;
            st.x = acc[0][i >> 1][i & 1];
            st.y = acc[1][i >> 1][i & 1];
            st.z = acc[2][i >> 1][i & 1];
            st.w = acc[3][i >> 1][i & 1];
            *(float4*)&qkv[b * 7168 + (ib * 8 + i) * 128 + ob * 4] = st;
        }
#pragma unroll
        for (int o = 0; o < 4; ++o) {
            float ps = 0.f, ps2 = 0.f;
#pragma unroll
            for (int ip = 0; ip < 4; ++ip) {
                ps  += acc[o][ip].x + acc[o][ip].y;
                ps2 += acc[o][ip].x * acc[o][ip].x + acc[o][ip].y * acc[o][ip].y;
            }
            atomicAdd(&s1[ob * 4 + o], ps);
            atomicAdd(&s2[ob * 4 + o], ps2);
        }
    }
    __syncthreads();
    if (t < 128) {
        float* dst = sums + (b & 7) * 256;
        atomicAdd(&dst[t], s1[t]);
        atomicAdd(&dst[128 + t], s2[t]);
    }
}

// ---------------- coef finalize (sums 8 slots) ----------------
__global__ void k_coef(const float* __restrict__ sums, const float* __restrict__ g,
                       const float* __restrict__ bb, float* __restrict__ coef,
                       int nch, float invM) {
    int o = blockIdx.x * blockDim.x + threadIdx.x;
    if (o < nch) {
        float a1 = 0.f, a2 = 0.f;
        for (int slot = 0; slot < 8; ++slot) {
            a1 += sums[slot * 2 * nch + o];
            a2 += sums[slot * 2 * nch + nch + o];
        }
        float mean = a1 * invM;
        float var  = fmaxf(a2 * invM - mean * mean, 0.f);
        float sc   = g[o] * rsqrtf(var + EPS);
        coef[o] = sc;
        coef[nch + o] = bb[o] - mean * sc;
    }
}

// ---------------- sim stats via Gram matrices (one wave per (b,g)) -----------
__global__ __launch_bounds__(256) void k_simstats(const float* __restrict__ qkv,
                                                  const float* __restrict__ qcoef,
                                                  const float* __restrict__ Rq,
                                                  const float* __restrict__ Rk,
                                                  const float* __restrict__ E2q,
                                                  const float* __restrict__ E2k,
                                                  float* __restrict__ ssum) {
    const int wid = threadIdx.x >> 6, lane = threadIdx.x & 63;
    const int unit = blockIdx.x * 4 + wid;
    const int b = unit >> 3, g = unit & 7;
    const int iL = lane < 56 ? lane : 55;
    const float valid = lane < 56 ? 1.f : 0.f;

    const float* row = qkv + b * 7168 + iL * 128 + g * 16;
    float4 q4 = *(const float4*)(row);
    float4 k4 = *(const float4*)(row + 4);
    const float4 aq = *(const float4*)&qcoef[g * 16];
    const float4 ak = *(const float4*)&qcoef[g * 16 + 4];
    const float4 cq = *(const float4*)&qcoef[QKV_CH + g * 16];
    const float4 ck = *(const float4*)&qcoef[QKV_CH + g * 16 + 4];
    float qv[4], kv[4];
    qv[0] = (q4.x * aq.x + cq.x) * valid;
    qv[1] = (q4.y * aq.y + cq.y) * valid;
    qv[2] = (q4.z * aq.z + cq.z) * valid;
    qv[3] = (q4.w * aq.w + cq.w) * valid;
    kv[0] = (k4.x * ak.x + ck.x) * valid;
    kv[1] = (k4.y * ak.y + ck.y) * valid;
    kv[2] = (k4.z * ak.z + ck.z) * valid;
    kv[3] = (k4.w * ak.w + ck.w) * valid;

    float4 rq = *(const float4*)&Rq[iL * 4];
    float4 rk = *(const float4*)&Rk[iL * 4];
    float e2q[10], e2k[10];
#pragma unroll
    for (int p = 0; p < 10; ++p) { e2q[p] = E2q[iL * 10 + p]; e2k[p] = E2k[iL * 10 + p]; }

    float red[32];
#pragma unroll
    for (int c = 0; c < 4; ++c) { red[c] = qv[c]; red[4 + c] = kv[c]; }
#pragma unroll
    for (int p = 0; p < 10; ++p) {
        red[8 + p]  = qv[PA[p]] * qv[PB[p]];
        red[18 + p] = kv[PA[p]] * kv[PB[p]];
    }
    {
        float rqa[4] = {rq.x, rq.y, rq.z, rq.w};
        float rka[4] = {rk.x, rk.y, rk.z, rk.w};
        float pq = 0.f, pk = 0.f, pq2 = 0.f, pk2 = 0.f;
#pragma unroll
        for (int c = 0; c < 4; ++c) { pq += qv[c] * rqa[c]; pk += kv[c] * rka[c]; }
#pragma unroll
        for (int p = 0; p < 10; ++p) {
            pq2 += PMf[p] * red[8 + p]  * e2q[p];
            pk2 += PMf[p] * red[18 + p] * e2k[p];
        }
        red[28] = pq; red[29] = pk; red[30] = pq2; red[31] = pk2;
    }
#pragma unroll
    for (int v = 0; v < 32; ++v) {
        float xv = red[v];
#pragma unroll
        for (int mk = 1; mk < 64; mk <<= 1) xv += __shfl_xor(xv, mk);
        red[v] = xv;
    }
    float sqk = 0.f, sqk2 = 0.f;
#pragma unroll
    for (int c = 0; c < 4; ++c) sqk += red[c] * red[4 + c];
#pragma unroll
    for (int p = 0; p < 10; ++p) sqk2 += PMf[p] * red[8 + p] * red[18 + p];
    if (lane == 0) {
        float* ss = ssum + (blockIdx.x & 7) * 48;
        atomicAdd(&ss[g], sqk);
        atomicAdd(&ss[8 + g], 0.1f * red[28]);
        atomicAdd(&ss[16 + g], 0.1f * red[29]);
        atomicAdd(&ss[SIM_CH + g], sqk2);
        atomicAdd(&ss[SIM_CH + 8 + g], 0.01f * red[30]);
        atomicAdd(&ss[SIM_CH + 16 + g], 0.01f * red[31]);
    }
}

// ---------------- attention: one wave per (b,g), lane = i, packed-fp32 --------
__global__ __launch_bounds__(256) void k_attn(const float* __restrict__ qkv,
                                              const float* __restrict__ qcoef,
                                              const float* __restrict__ scoef,
                                              const float* __restrict__ WQK,
                                              const float* __restrict__ WV,
                                              float* __restrict__ so,
                                              float* __restrict__ osums) {
    __shared__ float sm[4 * 1344];
    const int wid = threadIdx.x >> 6, lane = threadIdx.x & 63;
    const int unit = blockIdx.x * 4 + wid;
    const int b = unit >> 3, g = unit & 7;
    float* sl = sm + wid * 1344;    // planes of 224: k01,k23,v01,v23,v45,v67 (ext 112)
    const int iL = lane < 56 ? lane : 55;

    const float* row = qkv + b * 7168 + iL * 128 + g * 16;
    float4 q4  = *(const float4*)(row);
    float4 k4  = *(const float4*)(row + 4);
    float4 va4 = *(const float4*)(row + 8);
    float4 vb4 = *(const float4*)(row + 12);
    const float4 a0 = *(const float4*)&qcoef[g * 16];
    const float4 a1 = *(const float4*)&qcoef[g * 16 + 4];
    const float4 a2 = *(const float4*)&qcoef[g * 16 + 8];
    const float4 a3 = *(const float4*)&qcoef[g * 16 + 12];
    const float4 c0 = *(const float4*)&qcoef[QKV_CH + g * 16];
    const float4 c1 = *(const float4*)&qcoef[QKV_CH + g * 16 + 4];
    const float4 c2 = *(const float4*)&qcoef[QKV_CH + g * 16 + 8];
    const float4 c3 = *(const float4*)&qcoef[QKV_CH + g * 16 + 12];
    float qh[4];
    qh[0] = q4.x * a0.x + c0.x;  qh[1] = q4.y * a0.y + c0.y;
    qh[2] = q4.z * a0.z + c0.z;  qh[3] = q4.w * a0.w + c0.w;
    if (lane < 56) {
        float2 k01 = make_float2(k4.x * a1.x + c1.x, k4.y * a1.y + c1.y);
        float2 k23 = make_float2(k4.z * a1.z + c1.z, k4.w * a1.w + c1.w);
        float2 v01 = make_float2(va4.x * a2.x + c2.x, va4.y * a2.y + c2.y);
        float2 v23 = make_float2(va4.z * a2.z + c2.z, va4.w * a2.w + c2.w);
        float2 v45 = make_float2(vb4.x * a3.x + c3.x, vb4.y * a3.y + c3.y);
        float2 v67 = make_float2(vb4.z * a3.z + c3.z, vb4.w * a3.w + c3.w);
        *(float2*)&sl[          iL * 2] = k01;  *(float2*)&sl[          (iL + 56) * 2] = k01;
        *(float2*)&sl[ 224 +    iL * 2] = k23;  *(float2*)&sl[ 224 +    (iL + 56) * 2] = k23;
        *(float2*)&sl[ 448 +    iL * 2] = v01;  *(float2*)&sl[ 448 +    (iL + 56) * 2] = v01;
        *(float2*)&sl[ 672 +    iL * 2] = v23;  *(float2*)&sl[ 672 +    (iL + 56) * 2] = v23;
        *(float2*)&sl[ 896 +    iL * 2] = v45;  *(float2*)&sl[ 896 +    (iL + 56) * 2] = v45;
        *(float2*)&sl[1120 +    iL * 2] = v67;  *(float2*)&sl[1120 +    (iL + 56) * 2] = v67;
    }
    __builtin_amdgcn_s_waitcnt(0);

    const float aqk = scoef[g];
    const float cc  = scoef[SIM_CH + g] + scoef[SIM_CH + 8 + g] + scoef[SIM_CH + 16 + g];
    // hoisted per-lane packed operands
    v2f qa01 = (v2f){qh[0] * aqk, qh[1] * aqk};
    v2f qa23 = (v2f){qh[2] * aqk, qh[3] * aqk};
    v2f qd[4];
#pragma unroll
    for (int c = 0; c < 4; ++c) qd[c] = (v2f)(qh[c]);

    const float* wqk = WQK + g * 896;   // 56 x 16

    float l = 0.f;
    v2f sv01 = (v2f)(0.f), sv23 = (v2f)(0.f), sv45 = (v2f)(0.f), sv67 = (v2f)(0.f);
    v2f sep[8];
#pragma unroll
    for (int c = 0; c < 8; ++c) sep[c] = (v2f)(0.f);

#pragma unroll 4
    for (int s = 0; s < 56; ++s) {
        const int p2 = (iL + s) * 2;
        const v2f k01 = *(const v2f*)&sl[p2];
        const v2f k23 = *(const v2f*)&sl[224 + p2];
        const float* W = wqk + s * 16;        // uniform -> s_load
        // q-side: packed {lo,delta} accumulation
        v2f RQ = qd[0] * (*(const v2f*)&W[0]);
        RQ += qd[1] * (*(const v2f*)&W[2]);
        RQ += qd[2] * (*(const v2f*)&W[4]);
        RQ += qd[3] * (*(const v2f*)&W[6]);
        // k-side select + qk in one packed accumulator
        const bool wrap = (iL + s) >= 56;
        v2f tk01 = (v2f){wrap ? W[12] : W[8],  wrap ? W[13] : W[9]};
        v2f tk23 = (v2f){wrap ? W[14] : W[10], wrap ? W[15] : W[11]};
        v2f P = qa01 * k01;
        P += qa23 * k23;
        P += k01 * tk01;
        P += k23 * tk23;
        float arg = P.x + P.y + RQ.x + (wrap ? RQ.y : 0.f) + cc;
        float e = __expf(arg);
        l += e;
        float ew = wrap ? e : 0.f;
        v2f ee = (v2f){e, e};
        v2f eD = (v2f){e, ew};
        sv01 += ee * (*(const v2f*)&sl[448 + p2]);
        sv23 += ee * (*(const v2f*)&sl[672 + p2]);
        sv45 += ee * (*(const v2f*)&sl[896 + p2]);
        sv67 += ee * (*(const v2f*)&sl[1120 + p2]);
        const float* V = WV + s * 16;         // uniform -> s_load
#pragma unroll
        for (int c = 0; c < 8; ++c) sep[c] += eD * (*(const v2f*)&V[c * 2]);
    }
    const float inv = 1.f / l;
    float osv[8], ose[8];
    osv[0] = sv01.x * inv; osv[1] = sv01.y * inv;
    osv[2] = sv23.x * inv; osv[3] = sv23.y * inv;
    osv[4] = sv45.x * inv; osv[5] = sv45.y * inv;
    osv[6] = sv67.x * inv; osv[7] = sv67.y * inv;
#pragma unroll
    for (int c = 0; c < 8; ++c) ose[c] = (sep[c].x + sep[c].y) * (0.1f * inv);

    if (lane < 56) {
        float* op = so + b * 7168 + g * 16 * 56 + iL;
#pragma unroll
        for (int c = 0; c < 8; ++c) {
            op[(2 * c) * 56]     = osv[c];
            op[(2 * c + 1) * 56] = ose[c];
        }
    }
    const float valid = lane < 56 ? 1.f : 0.f;
    float red[32];
#pragma unroll
    for (int c = 0; c < 8; ++c) {
        red[c]      = osv[c] * valid;
        red[8 + c]  = ose[c] * valid;
        red[16 + c] = osv[c] * osv[c] * valid;
        red[24 + c] = ose[c] * ose[c] * valid;
    }
#pragma unroll
    for (int v = 0; v < 32; ++v) {
        float xv = red[v];
#pragma unroll
        for (int mk = 1; mk < 64; mk <<= 1) xv += __shfl_xor(xv, mk);
        red[v] = xv;
    }
    if (lane == 0) {
        float* dst = osums + (blockIdx.x & 7) * 256;
#pragma unroll
        for (int c = 0; c < 8; ++c) {
            atomicAdd(&dst[g * 16 + 2 * c],           red[c]);
            atomicAdd(&dst[g * 16 + 2 * c + 1],       red[8 + c]);
            atomicAdd(&dst[128 + g * 16 + 2 * c],     red[16 + c]);
            atomicAdd(&dst[128 + g * 16 + 2 * c + 1], red[24 + c]);
        }
    }
}

// ---------------- out-BN + pair-sum + transpose store ----------------
__global__ __launch_bounds__(256) void k_out(const float* __restrict__ so,
                                             const float* __restrict__ ocoef,
                                             float* __restrict__ out) {
    int idx = blockIdx.x * 256 + threadIdx.x;
    int t = idx % KW;
    int rest = idx / KW;
    int h = rest % KW;
    int rest2 = rest / KW;
    int d = rest2 & 31;
    int oc = rest2 >> 5;
    int b = d * KW + h;
    int o0 = 2 * oc;
    float v0 = so[(size_t)b * 7168 + o0 * KW + t];
    float v1 = so[(size_t)b * 7168 + (o0 + 1) * KW + t];
    v0 = v0 * ocoef[o0]     + ocoef[QKV_CH + o0];
    v1 = v1 * ocoef[o0 + 1] + ocoef[QKV_CH + o0 + 1];
    out[idx] = v0 + v1;
}

extern "C" void kernel_launch(void* const* d_in, const int* in_sizes, int n_in,
                              void* d_out, int out_size, void* d_ws, size_t ws_size,
                              hipStream_t stream) {
    const float* x     = (const float*)d_in[0];
    const float* wqkv  = (const float*)d_in[1];
    const float* rel   = (const float*)d_in[2];
    const float* g_qkv = (const float*)d_in[3];
    const float* b_qkv = (const float*)d_in[4];
    const float* g_sim = (const float*)d_in[5];
    const float* b_sim = (const float*)d_in[6];
    const float* g_out = (const float*)d_in[7];
    const float* b_out = (const float*)d_in[8];
    float* out = (float*)d_out;
    float* ws = (float*)d_ws;

    float* qkv_raw  = ws;                       // [b][i][o]
    float* so_raw   = ws + 12845056;            // [b][o][i]
    float* stats    = ws + 25690112;
    float* qkv_sums = stats;                    // 8 x 256
    float* sim_sums = stats + 2048;             // 8 x 48
    float* out_sums = stats + 2432;             // 8 x 256
    float* qkv_coef = stats + 4480;             // 256
    float* sim_coef = stats + 4736;             // 48
    float* out_coef = stats + 4784;             // 256
    float* tabs     = stats + 5040;             // R/E2 tables (1568)
    float* Rq  = tabs;
    float* Rk  = tabs + 224;
    float* E2q = tabs + 448;
    float* E2k = tabs + 1008;
    float* WQK = tabs + 1568;                   // 7168
    float* WV  = WQK + 7168;                    // 896

    hipMemsetAsync(stats, 0, 4480 * sizeof(float), stream);
    k_setup<<<1, 256, 0, stream>>>(rel, tabs);

    k_qkv<<<NB, 256, 0, stream>>>(x, wqkv, qkv_raw, qkv_sums);
    k_coef<<<1, 128, 0, stream>>>(qkv_sums, g_qkv, b_qkv, qkv_coef, QKV_CH,
                                  1.0f / 100352.0f);
    k_simstats<<<3584, 256, 0, stream>>>(qkv_raw, qkv_coef, Rq, Rk, E2q, E2k,
                                         sim_sums);
    k_coef<<<1, 128, 0, stream>>>(sim_sums, g_sim, b_sim, sim_coef, SIM_CH,
                                  1.0f / 5619712.0f);
    k_fold<<<1, 256, 0, stream>>>(rel, sim_coef, WQK, WV);
    k_attn<<<3584, 256, 0, stream>>>(qkv_raw, qkv_coef, sim_coef, WQK, WV,
                                     so_raw, out_sums);
    k_coef<<<1, 128, 0, stream>>>(out_sums, g_out, b_out, out_coef, QKV_CH,
                                  1.0f / 100352.0f);
    k_out<<<25088, 256, 0, stream>>>(so_raw, out_coef, out);
}

// Round 5
// 495.774 us; speedup vs baseline: 1.1063x; 1.1063x over previous
//
#include <hip/hip_runtime.h>
#include <math.h>

typedef float v2f __attribute__((ext_vector_type(2)));

constexpr int KW      = 56;
constexpr int NB      = 1792;
constexpr int QKV_CH  = 128;
constexpr int SIM_CH  = 24;
constexpr float EPS   = 1e-5f;

constexpr int   PA[10]  = {0,0,0,0,1,1,1,2,2,3};
constexpr int   PB[10]  = {0,1,2,3,1,2,3,2,3,3};
constexpr float PMf[10] = {1,2,2,2,1,2,2,1,2,1};

// ---------------- setup: rel-derived tables (all g-independent) ----------------
// Rq/Rk/E2q/E2k: sim-stat Gram tables.
// TAB[s][32]: [0..7]  {lo,d} q-side (lo=rel[c][55-s], d=rel[c][111-s]-lo, s>0)
//             [8..11] klo = rel[4+c][55+s]
//             [12..15] khi = rel[4+c][s-1] (0 for s=0)
//             [16..31] {lo,d} v-side (rel rows 8..15)
__global__ void k_setup(const float* __restrict__ rel, float* __restrict__ tabs) {
    const int t = threadIdx.x;
    float* Rq  = tabs;
    float* Rk  = tabs + 224;
    float* E2q = tabs + 448;
    float* E2k = tabs + 1008;
    float* TAB = tabs + 1568;
    for (int idx = t; idx < 448; idx += 256) {
        int which = idx / 224, r = idx % 224;
        int i = r >> 2, c = r & 3;
        const float* src = rel + (which * 4 + c) * 111;
        float s = 0.f;
        for (int tt = 0; tt < 56; ++tt) s += src[i + tt];
        (which ? Rk : Rq)[r] = s;
    }
    for (int idx = t; idx < 1120; idx += 256) {
        int which = idx / 560, r = idx % 560;
        int i = r / 10, p = r % 10;
        const float* sa = rel + (which * 4 + PA[p]) * 111;
        const float* sb = rel + (which * 4 + PB[p]) * 111;
        float s = 0.f;
        for (int tt = 0; tt < 56; ++tt) s += sa[i + tt] * sb[i + tt];
        (which ? E2k : E2q)[r] = s;
    }
    for (int s = t; s < 56; s += 256) {
        float* T = TAB + s * 32;
#pragma unroll
        for (int c = 0; c < 4; ++c) {
            float lo = rel[c * 111 + 55 - s];
            float hi = (s > 0) ? rel[c * 111 + 111 - s] : lo;
            T[c * 2]     = lo;
            T[c * 2 + 1] = hi - lo;
            T[8 + c]  = rel[(4 + c) * 111 + 55 + s];
            T[12 + c] = (s > 0) ? rel[(4 + c) * 111 + s - 1] : 0.f;
        }
#pragma unroll
        for (int c = 0; c < 8; ++c) {
            float lo = rel[(8 + c) * 111 + 55 - s];
            float hi = (s > 0) ? rel[(8 + c) * 111 + 111 - s] : lo;
            T[16 + c * 2]     = lo;
            T[16 + c * 2 + 1] = hi - lo;
        }
    }
}

// ---------------- Kernel A: qkv[b][i][o] = w @ x + per-channel stats ----------
__global__ __launch_bounds__(256) void k_qkv(const float* __restrict__ x,
                                             const float* __restrict__ w,
                                             float* __restrict__ qkv,
                                             float* __restrict__ sums) {
    __shared__ float xs[64 * KW];
    __shared__ float wt[64 * 128];
    __shared__ float s1[128], s2[128];
    const int b = blockIdx.x, t = threadIdx.x;

    if (t < 128) { s1[t] = 0.f; s2[t] = 0.f; }
    for (int idx = t; idx < 896; idx += 256) {
        int c = idx / 14, r = idx % 14;
        float4 v = *(const float4*)&x[c * 100352 + b * 56 + r * 4];
        *(float4*)&xs[c * 56 + r * 4] = v;
    }
    for (int idx = t; idx < 2048; idx += 256) {
        int o = idx >> 4, cq = idx & 15;
        float4 v = *(const float4*)&w[o * 64 + cq * 4];
        wt[(cq * 4 + 0) * 128 + o] = v.x;
        wt[(cq * 4 + 1) * 128 + o] = v.y;
        wt[(cq * 4 + 2) * 128 + o] = v.z;
        wt[(cq * 4 + 3) * 128 + o] = v.w;
    }
    __syncthreads();

    if (t < 224) {
        const int ob = t & 31, ib = t >> 5;
        v2f acc[4][4];
#pragma unroll
        for (int o = 0; o < 4; ++o)
#pragma unroll
            for (int ip = 0; ip < 4; ++ip) acc[o][ip] = (v2f)(0.f);
        for (int c = 0; c < 64; ++c) {
            float4 wv = *(const float4*)&wt[c * 128 + (ob << 2)];
            float4 x0 = *(const float4*)&xs[c * 56 + (ib << 3)];
            float4 x1 = *(const float4*)&xs[c * 56 + (ib << 3) + 4];
            v2f xp[4];
            xp[0] = (v2f){x0.x, x0.y}; xp[1] = (v2f){x0.z, x0.w};
            xp[2] = (v2f){x1.x, x1.y}; xp[3] = (v2f){x1.z, x1.w};
            v2f wd[4];
            wd[0] = (v2f)(wv.x); wd[1] = (v2f)(wv.y);
            wd[2] = (v2f)(wv.z); wd[3] = (v2f)(wv.w);
#pragma unroll
            for (int o = 0; o < 4; ++o)
#pragma unroll
                for (int ip = 0; ip < 4; ++ip)
                    acc[o][ip] += wd[o] * xp[ip];
        }
#pragma unroll
        for (int i = 0; i < 8; ++i) {
            float4 st;
            st.x = acc[0][i >> 1][i & 1];
            st.y = acc[1][i >> 1][i & 1];
            st.z = acc[2][i >> 1][i & 1];
            st.w = acc[3][i >> 1][i & 1];
            *(float4*)&qkv[b * 7168 + (ib * 8 + i) * 128 + ob * 4] = st;
        }
#pragma unroll
        for (int o = 0; o < 4; ++o) {
            float ps = 0.f, ps2 = 0.f;
#pragma unroll
            for (int ip = 0; ip < 4; ++ip) {
                ps  += acc[o][ip].x + acc[o][ip].y;
                ps2 += acc[o][ip].x * acc[o][ip].x + acc[o][ip].y * acc[o][ip].y;
            }
            atomicAdd(&s1[ob * 4 + o], ps);
            atomicAdd(&s2[ob * 4 + o], ps2);
        }
    }
    __syncthreads();
    if (t < 128) {
        float* dst = sums + (b & 7) * 256;
        atomicAdd(&dst[t], s1[t]);
        atomicAdd(&dst[128 + t], s2[t]);
    }
}

// ---------------- coef finalize (sums 8 slots) ----------------
__global__ void k_coef(const float* __restrict__ sums, const float* __restrict__ g,
                       const float* __restrict__ bb, float* __restrict__ coef,
                       int nch, float invM) {
    int o = blockIdx.x * blockDim.x + threadIdx.x;
    if (o < nch) {
        float a1 = 0.f, a2 = 0.f;
        for (int slot = 0; slot < 8; ++slot) {
            a1 += sums[slot * 2 * nch + o];
            a2 += sums[slot * 2 * nch + nch + o];
        }
        float mean = a1 * invM;
        float var  = fmaxf(a2 * invM - mean * mean, 0.f);
        float sc   = g[o] * rsqrtf(var + EPS);
        coef[o] = sc;
        coef[nch + o] = bb[o] - mean * sc;
    }
}

// ---------------- sim stats via Gram matrices (one wave per (b,g)) -----------
__global__ __launch_bounds__(256) void k_simstats(const float* __restrict__ qkv,
                                                  const float* __restrict__ qcoef,
                                                  const float* __restrict__ Rq,
                                                  const float* __restrict__ Rk,
                                                  const float* __restrict__ E2q,
                                                  const float* __restrict__ E2k,
                                                  float* __restrict__ ssum) {
    const int wid = threadIdx.x >> 6, lane = threadIdx.x & 63;
    const int unit = blockIdx.x * 4 + wid;
    const int b = unit >> 3, g = unit & 7;
    const int iL = lane < 56 ? lane : 55;
    const float valid = lane < 56 ? 1.f : 0.f;

    const float* row = qkv + b * 7168 + iL * 128 + g * 16;
    float4 q4 = *(const float4*)(row);
    float4 k4 = *(const float4*)(row + 4);
    const float4 aq = *(const float4*)&qcoef[g * 16];
    const float4 ak = *(const float4*)&qcoef[g * 16 + 4];
    const float4 cq = *(const float4*)&qcoef[QKV_CH + g * 16];
    const float4 ck = *(const float4*)&qcoef[QKV_CH + g * 16 + 4];
    float qv[4], kv[4];
    qv[0] = (q4.x * aq.x + cq.x) * valid;
    qv[1] = (q4.y * aq.y + cq.y) * valid;
    qv[2] = (q4.z * aq.z + cq.z) * valid;
    qv[3] = (q4.w * aq.w + cq.w) * valid;
    kv[0] = (k4.x * ak.x + ck.x) * valid;
    kv[1] = (k4.y * ak.y + ck.y) * valid;
    kv[2] = (k4.z * ak.z + ck.z) * valid;
    kv[3] = (k4.w * ak.w + ck.w) * valid;

    float4 rq = *(const float4*)&Rq[iL * 4];
    float4 rk = *(const float4*)&Rk[iL * 4];
    float e2q[10], e2k[10];
#pragma unroll
    for (int p = 0; p < 10; ++p) { e2q[p] = E2q[iL * 10 + p]; e2k[p] = E2k[iL * 10 + p]; }

    float red[32];
#pragma unroll
    for (int c = 0; c < 4; ++c) { red[c] = qv[c]; red[4 + c] = kv[c]; }
#pragma unroll
    for (int p = 0; p < 10; ++p) {
        red[8 + p]  = qv[PA[p]] * qv[PB[p]];
        red[18 + p] = kv[PA[p]] * kv[PB[p]];
    }
    {
        float rqa[4] = {rq.x, rq.y, rq.z, rq.w};
        float rka[4] = {rk.x, rk.y, rk.z, rk.w};
        float pq = 0.f, pk = 0.f, pq2 = 0.f, pk2 = 0.f;
#pragma unroll
        for (int c = 0; c < 4; ++c) { pq += qv[c] * rqa[c]; pk += kv[c] * rka[c]; }
#pragma unroll
        for (int p = 0; p < 10; ++p) {
            pq2 += PMf[p] * red[8 + p]  * e2q[p];
            pk2 += PMf[p] * red[18 + p] * e2k[p];
        }
        red[28] = pq; red[29] = pk; red[30] = pq2; red[31] = pk2;
    }
#pragma unroll
    for (int v = 0; v < 32; ++v) {
        float xv = red[v];
#pragma unroll
        for (int mk = 1; mk < 64; mk <<= 1) xv += __shfl_xor(xv, mk);
        red[v] = xv;
    }
    float sqk = 0.f, sqk2 = 0.f;
#pragma unroll
    for (int c = 0; c < 4; ++c) sqk += red[c] * red[4 + c];
#pragma unroll
    for (int p = 0; p < 10; ++p) sqk2 += PMf[p] * red[8 + p] * red[18 + p];
    if (lane == 0) {
        float* ss = ssum + (blockIdx.x & 7) * 48;
        atomicAdd(&ss[g], sqk);
        atomicAdd(&ss[8 + g], 0.1f * red[28]);
        atomicAdd(&ss[16 + g], 0.1f * red[29]);
        atomicAdd(&ss[SIM_CH + g], sqk2);
        atomicAdd(&ss[SIM_CH + 8 + g], 0.01f * red[30]);
        atomicAdd(&ss[SIM_CH + 16 + g], 0.01f * red[31]);
    }
}

// ---------------- attention: one wave per (b,g), packed fp32, shared 7KB table
__global__ __launch_bounds__(256) void k_attn(const float* __restrict__ qkv,
                                              const float* __restrict__ qcoef,
                                              const float* __restrict__ scoef,
                                              const float* __restrict__ TAB,
                                              float* __restrict__ so,
                                              float* __restrict__ osums) {
    __shared__ float sm[4 * 1344];
    const int wid = threadIdx.x >> 6, lane = threadIdx.x & 63;
    const int unit = blockIdx.x * 4 + wid;
    const int b = unit >> 3, g = unit & 7;
    float* sl = sm + wid * 1344;    // planes of 224: k01,k23,v01,v23,v45,v67 (ext 112)
    const int iL = lane < 56 ? lane : 55;

    const float* row = qkv + b * 7168 + iL * 128 + g * 16;
    float4 q4  = *(const float4*)(row);
    float4 k4  = *(const float4*)(row + 4);
    float4 va4 = *(const float4*)(row + 8);
    float4 vb4 = *(const float4*)(row + 12);
    const float4 a0 = *(const float4*)&qcoef[g * 16];
    const float4 a1 = *(const float4*)&qcoef[g * 16 + 4];
    const float4 a2 = *(const float4*)&qcoef[g * 16 + 8];
    const float4 a3 = *(const float4*)&qcoef[g * 16 + 12];
    const float4 c0 = *(const float4*)&qcoef[QKV_CH + g * 16];
    const float4 c1 = *(const float4*)&qcoef[QKV_CH + g * 16 + 4];
    const float4 c2 = *(const float4*)&qcoef[QKV_CH + g * 16 + 8];
    const float4 c3 = *(const float4*)&qcoef[QKV_CH + g * 16 + 12];
    float qh[4];
    qh[0] = q4.x * a0.x + c0.x;  qh[1] = q4.y * a0.y + c0.y;
    qh[2] = q4.z * a0.z + c0.z;  qh[3] = q4.w * a0.w + c0.w;
    if (lane < 56) {
        float2 k01 = make_float2(k4.x * a1.x + c1.x, k4.y * a1.y + c1.y);
        float2 k23 = make_float2(k4.z * a1.z + c1.z, k4.w * a1.w + c1.w);
        float2 v01 = make_float2(va4.x * a2.x + c2.x, va4.y * a2.y + c2.y);
        float2 v23 = make_float2(va4.z * a2.z + c2.z, va4.w * a2.w + c2.w);
        float2 v45 = make_float2(vb4.x * a3.x + c3.x, vb4.y * a3.y + c3.y);
        float2 v67 = make_float2(vb4.z * a3.z + c3.z, vb4.w * a3.w + c3.w);
        *(float2*)&sl[          iL * 2] = k01;  *(float2*)&sl[          (iL + 56) * 2] = k01;
        *(float2*)&sl[ 224 +    iL * 2] = k23;  *(float2*)&sl[ 224 +    (iL + 56) * 2] = k23;
        *(float2*)&sl[ 448 +    iL * 2] = v01;  *(float2*)&sl[ 448 +    (iL + 56) * 2] = v01;
        *(float2*)&sl[ 672 +    iL * 2] = v23;  *(float2*)&sl[ 672 +    (iL + 56) * 2] = v23;
        *(float2*)&sl[ 896 +    iL * 2] = v45;  *(float2*)&sl[ 896 +    (iL + 56) * 2] = v45;
        *(float2*)&sl[1120 +    iL * 2] = v67;  *(float2*)&sl[1120 +    (iL + 56) * 2] = v67;
    }
    __builtin_amdgcn_s_waitcnt(0);

    const float aqk = scoef[g];
    const float aqr = scoef[8 + g] * 0.1f;     // folded into qd splats
    const float akr = scoef[16 + g] * 0.1f;    // applied once per iter
    const float cc  = scoef[SIM_CH + g] + scoef[SIM_CH + 8 + g] + scoef[SIM_CH + 16 + g];
    v2f qa01 = (v2f){qh[0] * aqk, qh[1] * aqk};
    v2f qa23 = (v2f){qh[2] * aqk, qh[3] * aqk};
    v2f qd[4];
#pragma unroll
    for (int c = 0; c < 4; ++c) qd[c] = (v2f)(qh[c] * aqr);

    float l = 0.f;
    v2f sv01 = (v2f)(0.f), sv23 = (v2f)(0.f), sv45 = (v2f)(0.f), sv67 = (v2f)(0.f);
    v2f sep[8];
#pragma unroll
    for (int c = 0; c < 8; ++c) sep[c] = (v2f)(0.f);

#pragma unroll 4
    for (int s = 0; s < 56; ++s) {
        const int p2 = (iL + s) * 2;
        const v2f k01 = *(const v2f*)&sl[p2];
        const v2f k23 = *(const v2f*)&sl[224 + p2];
        const float* T = TAB + s * 32;        // uniform, 7KB total -> sL1 hit
        // q-side {lo,delta}, pre-scaled by aqr via qd
        v2f RQ = qd[0] * (*(const v2f*)&T[0]);
        RQ += qd[1] * (*(const v2f*)&T[2]);
        RQ += qd[2] * (*(const v2f*)&T[4]);
        RQ += qd[3] * (*(const v2f*)&T[6]);
        // k-side: two packed accumulators, select after horizontal add
        v2f KRlo = k01 * (*(const v2f*)&T[8]);
        KRlo += k23 * (*(const v2f*)&T[10]);
        v2f KRhi = k01 * (*(const v2f*)&T[12]);
        KRhi += k23 * (*(const v2f*)&T[14]);
        v2f P = qa01 * k01;
        P += qa23 * k23;
        const bool wrap = (iL + s) >= 56;
        float kr = wrap ? (KRhi.x + KRhi.y) : (KRlo.x + KRlo.y);
        float qr = RQ.x + (wrap ? RQ.y : 0.f);
        float arg = P.x + P.y + akr * kr + qr + cc;
        float e = __expf(arg);
        l += e;
        float ew = wrap ? e : 0.f;
        v2f ee = (v2f){e, e};
        v2f eD = (v2f){e, ew};
        sv01 += ee * (*(const v2f*)&sl[448 + p2]);
        sv23 += ee * (*(const v2f*)&sl[672 + p2]);
        sv45 += ee * (*(const v2f*)&sl[896 + p2]);
        sv67 += ee * (*(const v2f*)&sl[1120 + p2]);
#pragma unroll
        for (int c = 0; c < 8; ++c) sep[c] += eD * (*(const v2f*)&T[16 + c * 2]);
    }
    const float inv = 1.f / l;
    float osv[8], ose[8];
    osv[0] = sv01.x * inv; osv[1] = sv01.y * inv;
    osv[2] = sv23.x * inv; osv[3] = sv23.y * inv;
    osv[4] = sv45.x * inv; osv[5] = sv45.y * inv;
    osv[6] = sv67.x * inv; osv[7] = sv67.y * inv;
#pragma unroll
    for (int c = 0; c < 8; ++c) ose[c] = (sep[c].x + sep[c].y) * (0.1f * inv);

    if (lane < 56) {
        float* op = so + b * 7168 + g * 16 * 56 + iL;
#pragma unroll
        for (int c = 0; c < 8; ++c) {
            op[(2 * c) * 56]     = osv[c];
            op[(2 * c + 1) * 56] = ose[c];
        }
    }
    const float valid = lane < 56 ? 1.f : 0.f;
    float red[32];
#pragma unroll
    for (int c = 0; c < 8; ++c) {
        red[c]      = osv[c] * valid;
        red[8 + c]  = ose[c] * valid;
        red[16 + c] = osv[c] * osv[c] * valid;
        red[24 + c] = ose[c] * ose[c] * valid;
    }
#pragma unroll
    for (int v = 0; v < 32; ++v) {
        float xv = red[v];
#pragma unroll
        for (int mk = 1; mk < 64; mk <<= 1) xv += __shfl_xor(xv, mk);
        red[v] = xv;
    }
    if (lane == 0) {
        float* dst = osums + (blockIdx.x & 7) * 256;
#pragma unroll
        for (int c = 0; c < 8; ++c) {
            atomicAdd(&dst[g * 16 + 2 * c],           red[c]);
            atomicAdd(&dst[g * 16 + 2 * c + 1],       red[8 + c]);
            atomicAdd(&dst[128 + g * 16 + 2 * c],     red[16 + c]);
            atomicAdd(&dst[128 + g * 16 + 2 * c + 1], red[24 + c]);
        }
    }
}

// ---------------- out-BN + pair-sum + transpose store ----------------
__global__ __launch_bounds__(256) void k_out(const float* __restrict__ so,
                                             const float* __restrict__ ocoef,
                                             float* __restrict__ out) {
    int idx = blockIdx.x * 256 + threadIdx.x;
    int t = idx % KW;
    int rest = idx / KW;
    int h = rest % KW;
    int rest2 = rest / KW;
    int d = rest2 & 31;
    int oc = rest2 >> 5;
    int b = d * KW + h;
    int o0 = 2 * oc;
    float v0 = so[(size_t)b * 7168 + o0 * KW + t];
    float v1 = so[(size_t)b * 7168 + (o0 + 1) * KW + t];
    v0 = v0 * ocoef[o0]     + ocoef[QKV_CH + o0];
    v1 = v1 * ocoef[o0 + 1] + ocoef[QKV_CH + o0 + 1];
    out[idx] = v0 + v1;
}

extern "C" void kernel_launch(void* const* d_in, const int* in_sizes, int n_in,
                              void* d_out, int out_size, void* d_ws, size_t ws_size,
                              hipStream_t stream) {
    const float* x     = (const float*)d_in[0];
    const float* wqkv  = (const float*)d_in[1];
    const float* rel   = (const float*)d_in[2];
    const float* g_qkv = (const float*)d_in[3];
    const float* b_qkv = (const float*)d_in[4];
    const float* g_sim = (const float*)d_in[5];
    const float* b_sim = (const float*)d_in[6];
    const float* g_out = (const float*)d_in[7];
    const float* b_out = (const float*)d_in[8];
    float* out = (float*)d_out;
    float* ws = (float*)d_ws;

    float* qkv_raw  = ws;                       // [b][i][o]
    float* so_raw   = ws + 12845056;            // [b][o][i]
    float* stats    = ws + 25690112;
    float* qkv_sums = stats;                    // 8 x 256
    float* sim_sums = stats + 2048;             // 8 x 48
    float* out_sums = stats + 2432;             // 8 x 256
    float* qkv_coef = stats + 4480;             // 256
    float* sim_coef = stats + 4736;             // 48
    float* out_coef = stats + 4784;             // 256
    float* tabs     = stats + 5040;             // Rq/Rk/E2q/E2k (1568) + TAB (1792)
    float* Rq  = tabs;
    float* Rk  = tabs + 224;
    float* E2q = tabs + 448;
    float* E2k = tabs + 1008;
    float* TAB = tabs + 1568;

    hipMemsetAsync(stats, 0, 4480 * sizeof(float), stream);
    k_setup<<<1, 256, 0, stream>>>(rel, tabs);

    k_qkv<<<NB, 256, 0, stream>>>(x, wqkv, qkv_raw, qkv_sums);
    k_coef<<<1, 128, 0, stream>>>(qkv_sums, g_qkv, b_qkv, qkv_coef, QKV_CH,
                                  1.0f / 100352.0f);
    k_simstats<<<3584, 256, 0, stream>>>(qkv_raw, qkv_coef, Rq, Rk, E2q, E2k,
                                         sim_sums);
    k_coef<<<1, 128, 0, stream>>>(sim_sums, g_sim, b_sim, sim_coef, SIM_CH,
                                  1.0f / 5619712.0f);
    k_attn<<<3584, 256, 0, stream>>>(qkv_raw, qkv_coef, sim_coef, TAB,
                                     so_raw, out_sums);
    k_coef<<<1, 128, 0, stream>>>(out_sums, g_out, b_out, out_coef, QKV_CH,
                                  1.0f / 100352.0f);
    k_out<<<25088, 256, 0, stream>>>(so_raw, out_coef, out);
}

// Round 6
// 475.579 us; speedup vs baseline: 1.1533x; 1.0425x over previous
//
#include <hip/hip_runtime.h>
#include <math.h>

typedef float v2f __attribute__((ext_vector_type(2)));

constexpr int KW      = 56;
constexpr int NB      = 1792;
constexpr int QKV_CH  = 128;
constexpr int SIM_CH  = 24;
constexpr float EPS   = 1e-5f;

constexpr int   PA[10]  = {0,0,0,0,1,1,1,2,2,3};
constexpr int   PB[10]  = {0,1,2,3,1,2,3,2,3,3};
constexpr float PMf[10] = {1,2,2,2,1,2,2,1,2,1};

// ---------------- setup: rel-derived tables ----------------
// Rq/Rk/E2q/E2k: Gram tables for k_simstats.
// TABJ (1792 floats), d in [0,112), c in [0,4):
//   TQ4[d][c] = rel[c][d]          (qr:  d = 55+i-j)
//   TK4[d][c] = rel[4+c][110-d]    (kr:  j-i+55 = 110-d)
//   TVa[d][c] = rel[8+c][d]
//   TVb[d][c] = rel[12+c][d]
__global__ void k_setup(const float* __restrict__ rel, float* __restrict__ tabs) {
    const int t = threadIdx.x;
    float* Rq  = tabs;
    float* Rk  = tabs + 224;
    float* E2q = tabs + 448;
    float* E2k = tabs + 1008;
    float* TABJ = tabs + 1568;
    for (int idx = t; idx < 448; idx += 256) {
        int which = idx / 224, r = idx % 224;
        int i = r >> 2, c = r & 3;
        const float* src = rel + (which * 4 + c) * 111;
        float s = 0.f;
        for (int tt = 0; tt < 56; ++tt) s += src[i + tt];
        (which ? Rk : Rq)[r] = s;
    }
    for (int idx = t; idx < 1120; idx += 256) {
        int which = idx / 560, r = idx % 560;
        int i = r / 10, p = r % 10;
        const float* sa = rel + (which * 4 + PA[p]) * 111;
        const float* sb = rel + (which * 4 + PB[p]) * 111;
        float s = 0.f;
        for (int tt = 0; tt < 56; ++tt) s += sa[i + tt] * sb[i + tt];
        (which ? E2k : E2q)[r] = s;
    }
    for (int d = t; d < 112; d += 256) {
        bool v = d < 111;
#pragma unroll
        for (int c = 0; c < 4; ++c) {
            TABJ[d * 4 + c]        = v ? rel[c * 111 + d] : 0.f;
            TABJ[448 + d * 4 + c]  = v ? rel[(4 + c) * 111 + 110 - d] : 0.f;
            TABJ[896 + d * 4 + c]  = v ? rel[(8 + c) * 111 + d] : 0.f;
            TABJ[1344 + d * 4 + c] = v ? rel[(12 + c) * 111 + d] : 0.f;
        }
    }
}

// ---------------- Kernel A: qkv[b][i][o] = w @ x + per-channel stats ----------
__global__ __launch_bounds__(256) void k_qkv(const float* __restrict__ x,
                                             const float* __restrict__ w,
                                             float* __restrict__ qkv,
                                             float* __restrict__ sums) {
    __shared__ float xs[64 * KW];
    __shared__ float wt[64 * 128];
    __shared__ float s1[128], s2[128];
    const int b = blockIdx.x, t = threadIdx.x;

    if (t < 128) { s1[t] = 0.f; s2[t] = 0.f; }
    for (int idx = t; idx < 896; idx += 256) {
        int c = idx / 14, r = idx % 14;
        float4 v = *(const float4*)&x[c * 100352 + b * 56 + r * 4];
        *(float4*)&xs[c * 56 + r * 4] = v;
    }
    for (int idx = t; idx < 2048; idx += 256) {
        int o = idx >> 4, cq = idx & 15;
        float4 v = *(const float4*)&w[o * 64 + cq * 4];
        wt[(cq * 4 + 0) * 128 + o] = v.x;
        wt[(cq * 4 + 1) * 128 + o] = v.y;
        wt[(cq * 4 + 2) * 128 + o] = v.z;
        wt[(cq * 4 + 3) * 128 + o] = v.w;
    }
    __syncthreads();

    if (t < 224) {
        const int ob = t & 31, ib = t >> 5;
        v2f acc[4][4];
#pragma unroll
        for (int o = 0; o < 4; ++o)
#pragma unroll
            for (int ip = 0; ip < 4; ++ip) acc[o][ip] = (v2f)(0.f);
        for (int c = 0; c < 64; ++c) {
            float4 wv = *(const float4*)&wt[c * 128 + (ob << 2)];
            float4 x0 = *(const float4*)&xs[c * 56 + (ib << 3)];
            float4 x1 = *(const float4*)&xs[c * 56 + (ib << 3) + 4];
            v2f xp[4];
            xp[0] = (v2f){x0.x, x0.y}; xp[1] = (v2f){x0.z, x0.w};
            xp[2] = (v2f){x1.x, x1.y}; xp[3] = (v2f){x1.z, x1.w};
            v2f wd[4];
            wd[0] = (v2f)(wv.x); wd[1] = (v2f)(wv.y);
            wd[2] = (v2f)(wv.z); wd[3] = (v2f)(wv.w);
#pragma unroll
            for (int o = 0; o < 4; ++o)
#pragma unroll
                for (int ip = 0; ip < 4; ++ip)
                    acc[o][ip] += wd[o] * xp[ip];
        }
#pragma unroll
        for (int i = 0; i < 8; ++i) {
            float4 st;
            st.x = acc[0][i >> 1][i & 1];
            st.y = acc[1][i >> 1][i & 1];
            st.z = acc[2][i >> 1][i & 1];
            st.w = acc[3][i >> 1][i & 1];
            *(float4*)&qkv[b * 7168 + (ib * 8 + i) * 128 + ob * 4] = st;
        }
#pragma unroll
        for (int o = 0; o < 4; ++o) {
            float ps = 0.f, ps2 = 0.f;
#pragma unroll
            for (int ip = 0; ip < 4; ++ip) {
                ps  += acc[o][ip].x + acc[o][ip].y;
                ps2 += acc[o][ip].x * acc[o][ip].x + acc[o][ip].y * acc[o][ip].y;
            }
            atomicAdd(&s1[ob * 4 + o], ps);
            atomicAdd(&s2[ob * 4 + o], ps2);
        }
    }
    __syncthreads();
    if (t < 128) {
        float* dst = sums + (b & 7) * 256;
        atomicAdd(&dst[t], s1[t]);
        atomicAdd(&dst[128 + t], s2[t]);
    }
}

// ---------------- coef finalize (sums 8 slots) ----------------
__global__ void k_coef(const float* __restrict__ sums, const float* __restrict__ g,
                       const float* __restrict__ bb, float* __restrict__ coef,
                       int nch, float invM) {
    int o = blockIdx.x * blockDim.x + threadIdx.x;
    if (o < nch) {
        float a1 = 0.f, a2 = 0.f;
        for (int slot = 0; slot < 8; ++slot) {
            a1 += sums[slot * 2 * nch + o];
            a2 += sums[slot * 2 * nch + nch + o];
        }
        float mean = a1 * invM;
        float var  = fmaxf(a2 * invM - mean * mean, 0.f);
        float sc   = g[o] * rsqrtf(var + EPS);
        coef[o] = sc;
        coef[nch + o] = bb[o] - mean * sc;
    }
}

// ---------------- sim stats via Gram matrices (one wave per (b,g)) -----------
__global__ __launch_bounds__(256) void k_simstats(const float* __restrict__ qkv,
                                                  const float* __restrict__ qcoef,
                                                  const float* __restrict__ Rq,
                                                  const float* __restrict__ Rk,
                                                  const float* __restrict__ E2q,
                                                  const float* __restrict__ E2k,
                                                  float* __restrict__ ssum) {
    const int wid = threadIdx.x >> 6, lane = threadIdx.x & 63;
    const int unit = blockIdx.x * 4 + wid;
    const int b = unit >> 3, g = unit & 7;
    const int iL = lane < 56 ? lane : 55;
    const float valid = lane < 56 ? 1.f : 0.f;

    const float* row = qkv + b * 7168 + iL * 128 + g * 16;
    float4 q4 = *(const float4*)(row);
    float4 k4 = *(const float4*)(row + 4);
    const float4 aq = *(const float4*)&qcoef[g * 16];
    const float4 ak = *(const float4*)&qcoef[g * 16 + 4];
    const float4 cq = *(const float4*)&qcoef[QKV_CH + g * 16];
    const float4 ck = *(const float4*)&qcoef[QKV_CH + g * 16 + 4];
    float qv[4], kv[4];
    qv[0] = (q4.x * aq.x + cq.x) * valid;
    qv[1] = (q4.y * aq.y + cq.y) * valid;
    qv[2] = (q4.z * aq.z + cq.z) * valid;
    qv[3] = (q4.w * aq.w + cq.w) * valid;
    kv[0] = (k4.x * ak.x + ck.x) * valid;
    kv[1] = (k4.y * ak.y + ck.y) * valid;
    kv[2] = (k4.z * ak.z + ck.z) * valid;
    kv[3] = (k4.w * ak.w + ck.w) * valid;

    float4 rq = *(const float4*)&Rq[iL * 4];
    float4 rk = *(const float4*)&Rk[iL * 4];
    float e2q[10], e2k[10];
#pragma unroll
    for (int p = 0; p < 10; ++p) { e2q[p] = E2q[iL * 10 + p]; e2k[p] = E2k[iL * 10 + p]; }

    float red[32];
#pragma unroll
    for (int c = 0; c < 4; ++c) { red[c] = qv[c]; red[4 + c] = kv[c]; }
#pragma unroll
    for (int p = 0; p < 10; ++p) {
        red[8 + p]  = qv[PA[p]] * qv[PB[p]];
        red[18 + p] = kv[PA[p]] * kv[PB[p]];
    }
    {
        float rqa[4] = {rq.x, rq.y, rq.z, rq.w};
        float rka[4] = {rk.x, rk.y, rk.z, rk.w};
        float pq = 0.f, pk = 0.f, pq2 = 0.f, pk2 = 0.f;
#pragma unroll
        for (int c = 0; c < 4; ++c) { pq += qv[c] * rqa[c]; pk += kv[c] * rka[c]; }
#pragma unroll
        for (int p = 0; p < 10; ++p) {
            pq2 += PMf[p] * red[8 + p]  * e2q[p];
            pk2 += PMf[p] * red[18 + p] * e2k[p];
        }
        red[28] = pq; red[29] = pk; red[30] = pq2; red[31] = pk2;
    }
#pragma unroll
    for (int v = 0; v < 32; ++v) {
        float xv = red[v];
#pragma unroll
        for (int mk = 1; mk < 64; mk <<= 1) xv += __shfl_xor(xv, mk);
        red[v] = xv;
    }
    float sqk = 0.f, sqk2 = 0.f;
#pragma unroll
    for (int c = 0; c < 4; ++c) sqk += red[c] * red[4 + c];
#pragma unroll
    for (int p = 0; p < 10; ++p) sqk2 += PMf[p] * red[8 + p] * red[18 + p];
    if (lane == 0) {
        float* ss = ssum + (blockIdx.x & 7) * 48;
        atomicAdd(&ss[g], sqk);
        atomicAdd(&ss[8 + g], 0.1f * red[28]);
        atomicAdd(&ss[16 + g], 0.1f * red[29]);
        atomicAdd(&ss[SIM_CH + g], sqk2);
        atomicAdd(&ss[SIM_CH + 8 + g], 0.01f * red[30]);
        atomicAdd(&ss[SIM_CH + 16 + g], 0.01f * red[31]);
    }
}

// ---------------- attention: direct-j loop, all tables in LDS, zero VMEM/iter -
__global__ __launch_bounds__(256) void k_attn(const float* __restrict__ qkv,
                                              const float* __restrict__ qcoef,
                                              const float* __restrict__ scoef,
                                              const float* __restrict__ TABJ,
                                              float* __restrict__ so,
                                              float* __restrict__ osums) {
    // sm: [0,1792) tables TQ4|TK4|TVa|TVb; then 4 waves x 672: KS[56][4],VSa[56][4],VSb[56][4]
    __shared__ float sm[1792 + 4 * 672];
    const int wid = threadIdx.x >> 6, lane = threadIdx.x & 63;
    const int unit = blockIdx.x * 4 + wid;
    const int b = unit >> 3, g = unit & 7;
    const int iL = lane < 56 ? lane : 55;
    float* wsl = sm + 1792 + wid * 672;   // KS @0, VSa @224, VSb @448

    // stage shared tables (block-wide, 448 float4s)
    for (int idx = threadIdx.x; idx < 448; idx += 256)
        *(float4*)&sm[idx * 4] = *(const float4*)&TABJ[idx * 4];

    const float* row = qkv + b * 7168 + iL * 128 + g * 16;
    float4 q4  = *(const float4*)(row);
    float4 k4  = *(const float4*)(row + 4);
    float4 va4 = *(const float4*)(row + 8);
    float4 vb4 = *(const float4*)(row + 12);
    const float4 a0 = *(const float4*)&qcoef[g * 16];
    const float4 a1 = *(const float4*)&qcoef[g * 16 + 4];
    const float4 a2 = *(const float4*)&qcoef[g * 16 + 8];
    const float4 a3 = *(const float4*)&qcoef[g * 16 + 12];
    const float4 c0 = *(const float4*)&qcoef[QKV_CH + g * 16];
    const float4 c1 = *(const float4*)&qcoef[QKV_CH + g * 16 + 4];
    const float4 c2 = *(const float4*)&qcoef[QKV_CH + g * 16 + 8];
    const float4 c3 = *(const float4*)&qcoef[QKV_CH + g * 16 + 12];
    float qh[4];
    qh[0] = q4.x * a0.x + c0.x;  qh[1] = q4.y * a0.y + c0.y;
    qh[2] = q4.z * a0.z + c0.z;  qh[3] = q4.w * a0.w + c0.w;
    if (lane < 56) {
        float4 kh = make_float4(k4.x * a1.x + c1.x, k4.y * a1.y + c1.y,
                                k4.z * a1.z + c1.z, k4.w * a1.w + c1.w);
        float4 vh = make_float4(va4.x * a2.x + c2.x, va4.y * a2.y + c2.y,
                                va4.z * a2.z + c2.z, va4.w * a2.w + c2.w);
        float4 wh = make_float4(vb4.x * a3.x + c3.x, vb4.y * a3.y + c3.y,
                                vb4.z * a3.z + c3.z, vb4.w * a3.w + c3.w);
        *(float4*)&wsl[iL * 4]       = kh;
        *(float4*)&wsl[224 + iL * 4] = vh;
        *(float4*)&wsl[448 + iL * 4] = wh;
    }
    __syncthreads();

    const float aqk = scoef[g];
    const float aqr = scoef[8 + g] * 0.1f;
    const float akr = scoef[16 + g] * 0.1f;
    const float cc  = scoef[SIM_CH + g] + scoef[SIM_CH + 8 + g] + scoef[SIM_CH + 16 + g];
    const v2f qa01 = (v2f){qh[0] * aqk, qh[1] * aqk};
    const v2f qa23 = (v2f){qh[2] * aqk, qh[3] * aqk};
    const v2f qr01 = (v2f){qh[0] * aqr, qh[1] * aqr};
    const v2f qr23 = (v2f){qh[2] * aqr, qh[3] * aqr};

    // per-lane table base: index (55+iL-j)*4
    const float* pQ  = sm + (55 + iL) * 4;
    const float* pK  = pQ + 448;
    const float* pVa = pQ + 896;
    const float* pVb = pQ + 1344;

    float l = 0.f;
    v2f sv01 = (v2f)(0.f), sv23 = (v2f)(0.f), sv45 = (v2f)(0.f), sv67 = (v2f)(0.f);
    v2f se01 = (v2f)(0.f), se23 = (v2f)(0.f), se45 = (v2f)(0.f), se67 = (v2f)(0.f);

#pragma unroll 4
    for (int j = 0; j < 56; ++j) {
        const float4 kj  = *(const float4*)&wsl[j * 4];          // uniform -> broadcast
        const float4 vja = *(const float4*)&wsl[224 + j * 4];
        const float4 vjb = *(const float4*)&wsl[448 + j * 4];
        const int off = -j * 4;
        const float4 tq = *(const float4*)(pQ + off);            // per-lane stride-1
        const float4 tk = *(const float4*)(pK + off);
        const float4 ta = *(const float4*)(pVa + off);
        const float4 tb = *(const float4*)(pVb + off);
        v2f P = qa01 * (v2f){kj.x, kj.y};
        P += qa23 * (v2f){kj.z, kj.w};
        P += qr01 * (v2f){tq.x, tq.y};
        P += qr23 * (v2f){tq.z, tq.w};
        v2f KR = (v2f){kj.x, kj.y} * (v2f){tk.x, tk.y};
        KR += (v2f){kj.z, kj.w} * (v2f){tk.z, tk.w};
        float arg = P.x + P.y + akr * (KR.x + KR.y) + cc;
        float e = __expf(arg);
        l += e;
        v2f ee = (v2f){e, e};
        sv01 += ee * (v2f){vja.x, vja.y};
        sv23 += ee * (v2f){vja.z, vja.w};
        sv45 += ee * (v2f){vjb.x, vjb.y};
        sv67 += ee * (v2f){vjb.z, vjb.w};
        se01 += ee * (v2f){ta.x, ta.y};
        se23 += ee * (v2f){ta.z, ta.w};
        se45 += ee * (v2f){tb.x, tb.y};
        se67 += ee * (v2f){tb.z, tb.w};
    }
    const float inv = 1.f / l;
    const float inv1 = 0.1f * inv;
    float osv[8], ose[8];
    osv[0] = sv01.x * inv; osv[1] = sv01.y * inv;
    osv[2] = sv23.x * inv; osv[3] = sv23.y * inv;
    osv[4] = sv45.x * inv; osv[5] = sv45.y * inv;
    osv[6] = sv67.x * inv; osv[7] = sv67.y * inv;
    ose[0] = se01.x * inv1; ose[1] = se01.y * inv1;
    ose[2] = se23.x * inv1; ose[3] = se23.y * inv1;
    ose[4] = se45.x * inv1; ose[5] = se45.y * inv1;
    ose[6] = se67.x * inv1; ose[7] = se67.y * inv1;

    if (lane < 56) {
        float* op = so + b * 7168 + g * 16 * 56 + iL;
#pragma unroll
        for (int c = 0; c < 8; ++c) {
            op[(2 * c) * 56]     = osv[c];
            op[(2 * c + 1) * 56] = ose[c];
        }
    }
    const float valid = lane < 56 ? 1.f : 0.f;
    float red[32];
#pragma unroll
    for (int c = 0; c < 8; ++c) {
        red[c]      = osv[c] * valid;
        red[8 + c]  = ose[c] * valid;
        red[16 + c] = osv[c] * osv[c] * valid;
        red[24 + c] = ose[c] * ose[c] * valid;
    }
#pragma unroll
    for (int v = 0; v < 32; ++v) {
        float xv = red[v];
#pragma unroll
        for (int mk = 1; mk < 64; mk <<= 1) xv += __shfl_xor(xv, mk);
        red[v] = xv;
    }
    if (lane == 0) {
        float* dst = osums + (blockIdx.x & 7) * 256;
#pragma unroll
        for (int c = 0; c < 8; ++c) {
            atomicAdd(&dst[g * 16 + 2 * c],           red[c]);
            atomicAdd(&dst[g * 16 + 2 * c + 1],       red[8 + c]);
            atomicAdd(&dst[128 + g * 16 + 2 * c],     red[16 + c]);
            atomicAdd(&dst[128 + g * 16 + 2 * c + 1], red[24 + c]);
        }
    }
}

// ---------------- out-BN + pair-sum + transpose store ----------------
__global__ __launch_bounds__(256) void k_out(const float* __restrict__ so,
                                             const float* __restrict__ ocoef,
                                             float* __restrict__ out) {
    int idx = blockIdx.x * 256 + threadIdx.x;
    int t = idx % KW;
    int rest = idx / KW;
    int h = rest % KW;
    int rest2 = rest / KW;
    int d = rest2 & 31;
    int oc = rest2 >> 5;
    int b = d * KW + h;
    int o0 = 2 * oc;
    float v0 = so[(size_t)b * 7168 + o0 * KW + t];
    float v1 = so[(size_t)b * 7168 + (o0 + 1) * KW + t];
    v0 = v0 * ocoef[o0]     + ocoef[QKV_CH + o0];
    v1 = v1 * ocoef[o0 + 1] + ocoef[QKV_CH + o0 + 1];
    out[idx] = v0 + v1;
}

extern "C" void kernel_launch(void* const* d_in, const int* in_sizes, int n_in,
                              void* d_out, int out_size, void* d_ws, size_t ws_size,
                              hipStream_t stream) {
    const float* x     = (const float*)d_in[0];
    const float* wqkv  = (const float*)d_in[1];
    const float* rel   = (const float*)d_in[2];
    const float* g_qkv = (const float*)d_in[3];
    const float* b_qkv = (const float*)d_in[4];
    const float* g_sim = (const float*)d_in[5];
    const float* b_sim = (const float*)d_in[6];
    const float* g_out = (const float*)d_in[7];
    const float* b_out = (const float*)d_in[8];
    float* out = (float*)d_out;
    float* ws = (float*)d_ws;

    float* qkv_raw  = ws;                       // [b][i][o]
    float* so_raw   = ws + 12845056;            // [b][o][i]
    float* stats    = ws + 25690112;
    float* qkv_sums = stats;                    // 8 x 256
    float* sim_sums = stats + 2048;             // 8 x 48
    float* out_sums = stats + 2432;             // 8 x 256
    float* qkv_coef = stats + 4480;             // 256
    float* sim_coef = stats + 4736;             // 48
    float* out_coef = stats + 4784;             // 256
    float* tabs     = stats + 5040;             // Rq/Rk/E2q/E2k (1568) + TABJ (1792)
    float* Rq   = tabs;
    float* Rk   = tabs + 224;
    float* E2q  = tabs + 448;
    float* E2k  = tabs + 1008;
    float* TABJ = tabs + 1568;

    hipMemsetAsync(stats, 0, 4480 * sizeof(float), stream);
    k_setup<<<1, 256, 0, stream>>>(rel, tabs);

    k_qkv<<<NB, 256, 0, stream>>>(x, wqkv, qkv_raw, qkv_sums);
    k_coef<<<1, 128, 0, stream>>>(qkv_sums, g_qkv, b_qkv, qkv_coef, QKV_CH,
                                  1.0f / 100352.0f);
    k_simstats<<<3584, 256, 0, stream>>>(qkv_raw, qkv_coef, Rq, Rk, E2q, E2k,
                                         sim_sums);
    k_coef<<<1, 128, 0, stream>>>(sim_sums, g_sim, b_sim, sim_coef, SIM_CH,
                                  1.0f / 5619712.0f);
    k_attn<<<3584, 256, 0, stream>>>(qkv_raw, qkv_coef, sim_coef, TABJ,
                                     so_raw, out_sums);
    k_coef<<<1, 128, 0, stream>>>(out_sums, g_out, b_out, out_coef, QKV_CH,
                                  1.0f / 100352.0f);
    k_out<<<25088, 256, 0, stream>>>(so_raw, out_coef, out);
}

// Round 7
// 450.652 us; speedup vs baseline: 1.2171x; 1.0553x over previous
//
#include <hip/hip_runtime.h>
#include <math.h>

typedef float v2f __attribute__((ext_vector_type(2)));

constexpr int KW      = 56;
constexpr int NB      = 1792;
constexpr int QKV_CH  = 128;
constexpr int SIM_CH  = 24;
constexpr float EPS   = 1e-5f;

constexpr int   PA[10]  = {0,0,0,0,1,1,1,2,2,3};
constexpr int   PB[10]  = {0,1,2,3,1,2,3,2,3,3};
constexpr float PMf[10] = {1,2,2,2,1,2,2,1,2,1};

__device__ inline float rdlane(float v, int l) {
    return __int_as_float(__builtin_amdgcn_readlane(__float_as_int(v), l));
}

// ---------------- setup: rel-derived tables (8 blocks) ----------------
// TABJ (1792 floats), d in [0,112), c in [0,4):
//   TQ4[d][c] = rel[c][d]          (qr:  d = 55+i-j)
//   TK4[d][c] = rel[4+c][110-d]    (kr)
//   TVa[d][c] = rel[8+c][d]
//   TVb[d][c] = rel[12+c][d]
__global__ void k_setup(const float* __restrict__ rel, float* __restrict__ tabs) {
    const int t0 = blockIdx.x * 256 + threadIdx.x;
    const int STR = 8 * 256;
    float* Rq  = tabs;
    float* Rk  = tabs + 224;
    float* E2q = tabs + 448;
    float* E2k = tabs + 1008;
    float* TABJ = tabs + 1568;
    for (int idx = t0; idx < 448; idx += STR) {
        int which = idx / 224, r = idx % 224;
        int i = r >> 2, c = r & 3;
        const float* src = rel + (which * 4 + c) * 111;
        float s = 0.f;
        for (int tt = 0; tt < 56; ++tt) s += src[i + tt];
        (which ? Rk : Rq)[r] = s;
    }
    for (int idx = t0; idx < 1120; idx += STR) {
        int which = idx / 560, r = idx % 560;
        int i = r / 10, p = r % 10;
        const float* sa = rel + (which * 4 + PA[p]) * 111;
        const float* sb = rel + (which * 4 + PB[p]) * 111;
        float s = 0.f;
        for (int tt = 0; tt < 56; ++tt) s += sa[i + tt] * sb[i + tt];
        (which ? E2k : E2q)[r] = s;
    }
    for (int d = t0; d < 112; d += STR) {
        bool v = d < 111;
#pragma unroll
        for (int c = 0; c < 4; ++c) {
            TABJ[d * 4 + c]        = v ? rel[c * 111 + d] : 0.f;
            TABJ[448 + d * 4 + c]  = v ? rel[(4 + c) * 111 + 110 - d] : 0.f;
            TABJ[896 + d * 4 + c]  = v ? rel[(8 + c) * 111 + d] : 0.f;
            TABJ[1344 + d * 4 + c] = v ? rel[(12 + c) * 111 + d] : 0.f;
        }
    }
}

// ---------------- Kernel A: qkv[b][i][o] = w @ x + per-channel stats ----------
__global__ __launch_bounds__(256) void k_qkv(const float* __restrict__ x,
                                             const float* __restrict__ w,
                                             float* __restrict__ qkv,
                                             float* __restrict__ sums) {
    __shared__ float xs[64 * KW];
    __shared__ float wt[64 * 128];
    __shared__ float s1[128], s2[128];
    const int b = blockIdx.x, t = threadIdx.x;

    if (t < 128) { s1[t] = 0.f; s2[t] = 0.f; }
    for (int idx = t; idx < 896; idx += 256) {
        int c = idx / 14, r = idx % 14;
        float4 v = *(const float4*)&x[c * 100352 + b * 56 + r * 4];
        *(float4*)&xs[c * 56 + r * 4] = v;
    }
    for (int idx = t; idx < 2048; idx += 256) {
        int o = idx >> 4, cq = idx & 15;
        float4 v = *(const float4*)&w[o * 64 + cq * 4];
        wt[(cq * 4 + 0) * 128 + o] = v.x;
        wt[(cq * 4 + 1) * 128 + o] = v.y;
        wt[(cq * 4 + 2) * 128 + o] = v.z;
        wt[(cq * 4 + 3) * 128 + o] = v.w;
    }
    __syncthreads();

    if (t < 224) {
        const int ob = t & 31, ib = t >> 5;
        v2f acc[4][4];
#pragma unroll
        for (int o = 0; o < 4; ++o)
#pragma unroll
            for (int ip = 0; ip < 4; ++ip) acc[o][ip] = (v2f)(0.f);
        for (int c = 0; c < 64; ++c) {
            float4 wv = *(const float4*)&wt[c * 128 + (ob << 2)];
            float4 x0 = *(const float4*)&xs[c * 56 + (ib << 3)];
            float4 x1 = *(const float4*)&xs[c * 56 + (ib << 3) + 4];
            v2f xp[4];
            xp[0] = (v2f){x0.x, x0.y}; xp[1] = (v2f){x0.z, x0.w};
            xp[2] = (v2f){x1.x, x1.y}; xp[3] = (v2f){x1.z, x1.w};
            v2f wd[4];
            wd[0] = (v2f)(wv.x); wd[1] = (v2f)(wv.y);
            wd[2] = (v2f)(wv.z); wd[3] = (v2f)(wv.w);
#pragma unroll
            for (int o = 0; o < 4; ++o)
#pragma unroll
                for (int ip = 0; ip < 4; ++ip)
                    acc[o][ip] += wd[o] * xp[ip];
        }
#pragma unroll
        for (int i = 0; i < 8; ++i) {
            float4 st;
            st.x = acc[0][i >> 1][i & 1];
            st.y = acc[1][i >> 1][i & 1];
            st.z = acc[2][i >> 1][i & 1];
            st.w = acc[3][i >> 1][i & 1];
            *(float4*)&qkv[b * 7168 + (ib * 8 + i) * 128 + ob * 4] = st;
        }
#pragma unroll
        for (int o = 0; o < 4; ++o) {
            float ps = 0.f, ps2 = 0.f;
#pragma unroll
            for (int ip = 0; ip < 4; ++ip) {
                ps  += acc[o][ip].x + acc[o][ip].y;
                ps2 += acc[o][ip].x * acc[o][ip].x + acc[o][ip].y * acc[o][ip].y;
            }
            atomicAdd(&s1[ob * 4 + o], ps);
            atomicAdd(&s2[ob * 4 + o], ps2);
        }
    }
    __syncthreads();
    if (t < 128) {
        float* dst = sums + (b & 7) * 256;
        atomicAdd(&dst[t], s1[t]);
        atomicAdd(&dst[128 + t], s2[t]);
    }
}

// ---------------- coef finalize (sums 8 slots) ----------------
__global__ void k_coef(const float* __restrict__ sums, const float* __restrict__ g,
                       const float* __restrict__ bb, float* __restrict__ coef,
                       int nch, float invM) {
    int o = blockIdx.x * blockDim.x + threadIdx.x;
    if (o < nch) {
        float a1 = 0.f, a2 = 0.f;
        for (int slot = 0; slot < 8; ++slot) {
            a1 += sums[slot * 2 * nch + o];
            a2 += sums[slot * 2 * nch + nch + o];
        }
        float mean = a1 * invM;
        float var  = fmaxf(a2 * invM - mean * mean, 0.f);
        float sc   = g[o] * rsqrtf(var + EPS);
        coef[o] = sc;
        coef[nch + o] = bb[o] - mean * sc;
    }
}

// ---------------- sim stats via Gram matrices (one wave per (b,g)) -----------
__global__ __launch_bounds__(256) void k_simstats(const float* __restrict__ qkv,
                                                  const float* __restrict__ qcoef,
                                                  const float* __restrict__ Rq,
                                                  const float* __restrict__ Rk,
                                                  const float* __restrict__ E2q,
                                                  const float* __restrict__ E2k,
                                                  float* __restrict__ ssum) {
    const int wid = threadIdx.x >> 6, lane = threadIdx.x & 63;
    const int unit = blockIdx.x * 4 + wid;
    const int b = unit >> 3, g = unit & 7;
    const int iL = lane < 56 ? lane : 55;
    const float valid = lane < 56 ? 1.f : 0.f;

    const float* row = qkv + b * 7168 + iL * 128 + g * 16;
    float4 q4 = *(const float4*)(row);
    float4 k4 = *(const float4*)(row + 4);
    const float4 aq = *(const float4*)&qcoef[g * 16];
    const float4 ak = *(const float4*)&qcoef[g * 16 + 4];
    const float4 cq = *(const float4*)&qcoef[QKV_CH + g * 16];
    const float4 ck = *(const float4*)&qcoef[QKV_CH + g * 16 + 4];
    float qv[4], kv[4];
    qv[0] = (q4.x * aq.x + cq.x) * valid;
    qv[1] = (q4.y * aq.y + cq.y) * valid;
    qv[2] = (q4.z * aq.z + cq.z) * valid;
    qv[3] = (q4.w * aq.w + cq.w) * valid;
    kv[0] = (k4.x * ak.x + ck.x) * valid;
    kv[1] = (k4.y * ak.y + ck.y) * valid;
    kv[2] = (k4.z * ak.z + ck.z) * valid;
    kv[3] = (k4.w * ak.w + ck.w) * valid;

    float4 rq = *(const float4*)&Rq[iL * 4];
    float4 rk = *(const float4*)&Rk[iL * 4];
    float e2q[10], e2k[10];
#pragma unroll
    for (int p = 0; p < 10; ++p) { e2q[p] = E2q[iL * 10 + p]; e2k[p] = E2k[iL * 10 + p]; }

    float red[32];
#pragma unroll
    for (int c = 0; c < 4; ++c) { red[c] = qv[c]; red[4 + c] = kv[c]; }
#pragma unroll
    for (int p = 0; p < 10; ++p) {
        red[8 + p]  = qv[PA[p]] * qv[PB[p]];
        red[18 + p] = kv[PA[p]] * kv[PB[p]];
    }
    {
        float rqa[4] = {rq.x, rq.y, rq.z, rq.w};
        float rka[4] = {rk.x, rk.y, rk.z, rk.w};
        float pq = 0.f, pk = 0.f, pq2 = 0.f, pk2 = 0.f;
#pragma unroll
        for (int c = 0; c < 4; ++c) { pq += qv[c] * rqa[c]; pk += kv[c] * rka[c]; }
#pragma unroll
        for (int p = 0; p < 10; ++p) {
            pq2 += PMf[p] * red[8 + p]  * e2q[p];
            pk2 += PMf[p] * red[18 + p] * e2k[p];
        }
        red[28] = pq; red[29] = pk; red[30] = pq2; red[31] = pk2;
    }
#pragma unroll
    for (int v = 0; v < 32; ++v) {
        float xv = red[v];
#pragma unroll
        for (int mk = 1; mk < 64; mk <<= 1) xv += __shfl_xor(xv, mk);
        red[v] = xv;
    }
    float sqk = 0.f, sqk2 = 0.f;
#pragma unroll
    for (int c = 0; c < 4; ++c) sqk += red[c] * red[4 + c];
#pragma unroll
    for (int p = 0; p < 10; ++p) sqk2 += PMf[p] * red[8 + p] * red[18 + p];
    if (lane == 0) {
        float* ss = ssum + (blockIdx.x & 7) * 48;
        atomicAdd(&ss[g], sqk);
        atomicAdd(&ss[8 + g], 0.1f * red[28]);
        atomicAdd(&ss[16 + g], 0.1f * red[29]);
        atomicAdd(&ss[SIM_CH + g], sqk2);
        atomicAdd(&ss[SIM_CH + 8 + g], 0.01f * red[30]);
        atomicAdd(&ss[SIM_CH + 16 + g], 0.01f * red[31]);
    }
}

// -------- attention: direct-j loop; k/v via readlane; tables in LDS ----------
__global__ __launch_bounds__(256) void k_attn(const float* __restrict__ qkv,
                                              const float* __restrict__ qcoef,
                                              const float* __restrict__ scoef,
                                              const float* __restrict__ TABJ,
                                              float* __restrict__ sv2,
                                              float* __restrict__ sve2,
                                              float* __restrict__ osums) {
    __shared__ float T[1792];
    const int wid = threadIdx.x >> 6, lane = threadIdx.x & 63;
    const int unit = blockIdx.x * 4 + wid;
    const int b = unit >> 3, g = unit & 7;
    const int iL = lane < 56 ? lane : 55;

    for (int idx = threadIdx.x; idx < 448; idx += 256)
        *(float4*)&T[idx * 4] = *(const float4*)&TABJ[idx * 4];

    const float* row = qkv + b * 7168 + iL * 128 + g * 16;
    float4 q4  = *(const float4*)(row);
    float4 k4  = *(const float4*)(row + 4);
    float4 va4 = *(const float4*)(row + 8);
    float4 vb4 = *(const float4*)(row + 12);
    const float4 a0 = *(const float4*)&qcoef[g * 16];
    const float4 a1 = *(const float4*)&qcoef[g * 16 + 4];
    const float4 a2 = *(const float4*)&qcoef[g * 16 + 8];
    const float4 a3 = *(const float4*)&qcoef[g * 16 + 12];
    const float4 c0 = *(const float4*)&qcoef[QKV_CH + g * 16];
    const float4 c1 = *(const float4*)&qcoef[QKV_CH + g * 16 + 4];
    const float4 c2 = *(const float4*)&qcoef[QKV_CH + g * 16 + 8];
    const float4 c3 = *(const float4*)&qcoef[QKV_CH + g * 16 + 12];
    // BN'd per-lane values (lane j holds k_hat[j], v_hat[j], w_hat[j])
    float4 kh, vh, wh;
    kh.x = k4.x * a1.x + c1.x;  kh.y = k4.y * a1.y + c1.y;
    kh.z = k4.z * a1.z + c1.z;  kh.w = k4.w * a1.w + c1.w;
    vh.x = va4.x * a2.x + c2.x; vh.y = va4.y * a2.y + c2.y;
    vh.z = va4.z * a2.z + c2.z; vh.w = va4.w * a2.w + c2.w;
    wh.x = vb4.x * a3.x + c3.x; wh.y = vb4.y * a3.y + c3.y;
    wh.z = vb4.z * a3.z + c3.z; wh.w = vb4.w * a3.w + c3.w;
    float qh[4];
    qh[0] = q4.x * a0.x + c0.x;  qh[1] = q4.y * a0.y + c0.y;
    qh[2] = q4.z * a0.z + c0.z;  qh[3] = q4.w * a0.w + c0.w;
    __syncthreads();

    const float aqk = scoef[g];
    const float aqr = scoef[8 + g] * 0.1f;
    const float akr = scoef[16 + g] * 0.1f;
    const float cc  = scoef[SIM_CH + g] + scoef[SIM_CH + 8 + g] + scoef[SIM_CH + 16 + g];
    const float qa0 = qh[0] * aqk, qa1 = qh[1] * aqk, qa2 = qh[2] * aqk, qa3 = qh[3] * aqk;
    const v2f qr01 = (v2f){qh[0] * aqr, qh[1] * aqr};
    const v2f qr23 = (v2f){qh[2] * aqr, qh[3] * aqr};

    float l = 0.f;
    float sv[8];
#pragma unroll
    for (int c = 0; c < 8; ++c) sv[c] = 0.f;
    v2f se01 = (v2f)(0.f), se23 = (v2f)(0.f), se45 = (v2f)(0.f), se67 = (v2f)(0.f);

#pragma unroll 4
    for (int j = 0; j < 56; ++j) {
        const float k0 = rdlane(kh.x, j), k1 = rdlane(kh.y, j);
        const float k2 = rdlane(kh.z, j), k3 = rdlane(kh.w, j);
        const float v0 = rdlane(vh.x, j), v1 = rdlane(vh.y, j);
        const float v2 = rdlane(vh.z, j), v3 = rdlane(vh.w, j);
        const float w0 = rdlane(wh.x, j), w1 = rdlane(wh.y, j);
        const float w2 = rdlane(wh.z, j), w3 = rdlane(wh.w, j);
        const int off = (55 + iL - j) * 4;
        const float4 tq = *(const float4*)&T[off];
        const float4 tk = *(const float4*)&T[448 + off];
        const float4 ta = *(const float4*)&T[896 + off];
        const float4 tb = *(const float4*)&T[1344 + off];
        v2f QR = qr01 * (v2f){tq.x, tq.y};
        QR += qr23 * (v2f){tq.z, tq.w};
        float qk = cc + qa0 * k0 + qa1 * k1 + qa2 * k2 + qa3 * k3;
        float kr = k0 * tk.x + k1 * tk.y + k2 * tk.z + k3 * tk.w;
        float arg = qk + QR.x + QR.y + akr * kr;
        float e = __expf(arg);
        l += e;
        sv[0] += e * v0; sv[1] += e * v1; sv[2] += e * v2; sv[3] += e * v3;
        sv[4] += e * w0; sv[5] += e * w1; sv[6] += e * w2; sv[7] += e * w3;
        v2f ee = (v2f){e, e};
        se01 += ee * (v2f){ta.x, ta.y};
        se23 += ee * (v2f){ta.z, ta.w};
        se45 += ee * (v2f){tb.x, tb.y};
        se67 += ee * (v2f){tb.z, tb.w};
    }
    const float inv = 1.f / l;
    const float inv1 = 0.1f * inv;
    float osv[8], ose[8];
#pragma unroll
    for (int c = 0; c < 8; ++c) osv[c] = sv[c] * inv;
    ose[0] = se01.x * inv1; ose[1] = se01.y * inv1;
    ose[2] = se23.x * inv1; ose[3] = se23.y * inv1;
    ose[4] = se45.x * inv1; ose[5] = se45.y * inv1;
    ose[6] = se67.x * inv1; ose[7] = se67.y * inv1;

    if (lane < 56) {
        // output-layout stores: idx = ((g*8+c)*1792 + b)*56 + i
        size_t base = ((size_t)(g * 8) * 1792 + b) * 56 + iL;
#pragma unroll
        for (int c = 0; c < 8; ++c) {
            sv2[base + (size_t)c * 100352]  = osv[c];
            sve2[base + (size_t)c * 100352] = ose[c];
        }
    }
    const float valid = lane < 56 ? 1.f : 0.f;
    float red[32];
#pragma unroll
    for (int c = 0; c < 8; ++c) {
        red[c]      = osv[c] * valid;
        red[8 + c]  = ose[c] * valid;
        red[16 + c] = osv[c] * osv[c] * valid;
        red[24 + c] = ose[c] * ose[c] * valid;
    }
#pragma unroll
    for (int v = 0; v < 32; ++v) {
        float xv = red[v];
#pragma unroll
        for (int mk = 1; mk < 64; mk <<= 1) xv += __shfl_xor(xv, mk);
        red[v] = xv;
    }
    if (lane == 0) {
        float* dst = osums + (blockIdx.x & 7) * 256;
#pragma unroll
        for (int c = 0; c < 8; ++c) {
            atomicAdd(&dst[g * 16 + 2 * c],           red[c]);
            atomicAdd(&dst[g * 16 + 2 * c + 1],       red[8 + c]);
            atomicAdd(&dst[128 + g * 16 + 2 * c],     red[16 + c]);
            atomicAdd(&dst[128 + g * 16 + 2 * c + 1], red[24 + c]);
        }
    }
}

// ---------------- out: streaming affine combine, fully coalesced --------------
__global__ __launch_bounds__(256) void k_out(const float* __restrict__ sv2,
                                             const float* __restrict__ sve2,
                                             const float* __restrict__ ocoef,
                                             float* __restrict__ out) {
    int e4 = blockIdx.x * 256 + threadIdx.x;     // 1,605,632 float4 elements
    int i0 = e4 * 4;
    int oc = i0 / 100352;
    int o0 = 2 * oc;
    float A = ocoef[o0], B = ocoef[o0 + 1];
    float C = ocoef[QKV_CH + o0] + ocoef[QKV_CH + o0 + 1];
    float4 v0 = *(const float4*)&sv2[i0];
    float4 v1 = *(const float4*)&sve2[i0];
    float4 r;
    r.x = A * v0.x + B * v1.x + C;
    r.y = A * v0.y + B * v1.y + C;
    r.z = A * v0.z + B * v1.z + C;
    r.w = A * v0.w + B * v1.w + C;
    *(float4*)&out[i0] = r;
}

extern "C" void kernel_launch(void* const* d_in, const int* in_sizes, int n_in,
                              void* d_out, int out_size, void* d_ws, size_t ws_size,
                              hipStream_t stream) {
    const float* x     = (const float*)d_in[0];
    const float* wqkv  = (const float*)d_in[1];
    const float* rel   = (const float*)d_in[2];
    const float* g_qkv = (const float*)d_in[3];
    const float* b_qkv = (const float*)d_in[4];
    const float* g_sim = (const float*)d_in[5];
    const float* b_sim = (const float*)d_in[6];
    const float* g_out = (const float*)d_in[7];
    const float* b_out = (const float*)d_in[8];
    float* out = (float*)d_out;
    float* ws = (float*)d_ws;

    float* qkv_raw  = ws;                       // [b][i][o]  12,845,056
    float* sv2      = ws + 12845056;            // out-layout  6,422,528
    float* sve2     = ws + 19267584;            // out-layout  6,422,528
    float* stats    = ws + 25690112;
    float* qkv_sums = stats;                    // 8 x 256
    float* sim_sums = stats + 2048;             // 8 x 48
    float* out_sums = stats + 2432;             // 8 x 256
    float* qkv_coef = stats + 4480;             // 256
    float* sim_coef = stats + 4736;             // 48
    float* out_coef = stats + 4784;             // 256
    float* tabs     = stats + 5040;             // Rq/Rk/E2q/E2k (1568) + TABJ (1792)
    float* Rq   = tabs;
    float* Rk   = tabs + 224;
    float* E2q  = tabs + 448;
    float* E2k  = tabs + 1008;
    float* TABJ = tabs + 1568;

    hipMemsetAsync(stats, 0, 4480 * sizeof(float), stream);
    k_setup<<<8, 256, 0, stream>>>(rel, tabs);

    k_qkv<<<NB, 256, 0, stream>>>(x, wqkv, qkv_raw, qkv_sums);
    k_coef<<<1, 128, 0, stream>>>(qkv_sums, g_qkv, b_qkv, qkv_coef, QKV_CH,
                                  1.0f / 100352.0f);
    k_simstats<<<3584, 256, 0, stream>>>(qkv_raw, qkv_coef, Rq, Rk, E2q, E2k,
                                         sim_sums);
    k_coef<<<1, 128, 0, stream>>>(sim_sums, g_sim, b_sim, sim_coef, SIM_CH,
                                  1.0f / 5619712.0f);
    k_attn<<<3584, 256, 0, stream>>>(qkv_raw, qkv_coef, sim_coef, TABJ,
                                     sv2, sve2, out_sums);
    k_coef<<<1, 128, 0, stream>>>(out_sums, g_out, b_out, out_coef, QKV_CH,
                                  1.0f / 100352.0f);
    k_out<<<6272, 256, 0, stream>>>(sv2, sve2, out_coef, out);
}

// Round 8
// 447.147 us; speedup vs baseline: 1.2267x; 1.0078x over previous
//
#include <hip/hip_runtime.h>
#include <math.h>

typedef float v2f __attribute__((ext_vector_type(2)));

constexpr int KW      = 56;
constexpr int NB      = 1792;
constexpr int QKV_CH  = 128;
constexpr int SIM_CH  = 24;
constexpr float EPS   = 1e-5f;

constexpr int   PA[10]  = {0,0,0,0,1,1,1,2,2,3};
constexpr int   PB[10]  = {0,1,2,3,1,2,3,2,3,3};
constexpr float PMf[10] = {1,2,2,2,1,2,2,1,2,1};

__device__ inline float rdlane(float v, int l) {
    return __int_as_float(__builtin_amdgcn_readlane(__float_as_int(v), l));
}
__device__ inline unsigned bfr(float f) {            // fp32 -> bf16 (RNE)
    unsigned u = __float_as_uint(f);
    return (u + 0x7fffu + ((u >> 16) & 1u)) >> 16;
}
__device__ inline unsigned pk2(float a, float b) {   // {lo=a, hi=b}
    return bfr(a) | (bfr(b) << 16);
}
__device__ inline float blo(unsigned u) { return __uint_as_float(u << 16); }
__device__ inline float bhi(unsigned u) { return __uint_as_float(u & 0xffff0000u); }

// ---- Kernel A: qkv[b][i][o] = w @ x + per-channel stats; blocks>=NB do setup --
__global__ __launch_bounds__(256) void k_qkv(const float* __restrict__ x,
                                             const float* __restrict__ w,
                                             const float* __restrict__ rel,
                                             float* __restrict__ qkv,
                                             float* __restrict__ sums,
                                             float* __restrict__ tabs) {
    const int t = threadIdx.x;
    if (blockIdx.x >= NB) {
        // ---------- setup path: rel-derived tables (8 blocks) ----------
        const int t0 = (blockIdx.x - NB) * 256 + t;
        const int STR = 8 * 256;
        float* Rq  = tabs;
        float* Rk  = tabs + 224;
        float* E2q = tabs + 448;
        float* E2k = tabs + 1008;
        uint4* T2  = (uint4*)(tabs + 1568);      // 224 uint4: [0,112) QK, [112,224) VV
        for (int idx = t0; idx < 448; idx += STR) {
            int which = idx / 224, r = idx % 224;
            int i = r >> 2, c = r & 3;
            const float* src = rel + (which * 4 + c) * 111;
            float s = 0.f;
            for (int tt = 0; tt < 56; ++tt) s += src[i + tt];
            (which ? Rk : Rq)[r] = s;
        }
        for (int idx = t0; idx < 1120; idx += STR) {
            int which = idx / 560, r = idx % 560;
            int i = r / 10, p = r % 10;
            const float* sa = rel + (which * 4 + PA[p]) * 111;
            const float* sb = rel + (which * 4 + PB[p]) * 111;
            float s = 0.f;
            for (int tt = 0; tt < 56; ++tt) s += sa[i + tt] * sb[i + tt];
            (which ? E2k : E2q)[r] = s;
        }
        for (int d = t0; d < 112; d += STR) {
            bool v = d < 111;
            float tq[4], tk[4], ta[4], tb[4];
#pragma unroll
            for (int c = 0; c < 4; ++c) {
                tq[c] = v ? rel[c * 111 + d] : 0.f;
                tk[c] = v ? rel[(4 + c) * 111 + 110 - d] : 0.f;
                ta[c] = v ? rel[(8 + c) * 111 + d] : 0.f;
                tb[c] = v ? rel[(12 + c) * 111 + d] : 0.f;
            }
            T2[d]       = make_uint4(pk2(tq[0], tq[1]), pk2(tq[2], tq[3]),
                                     pk2(tk[0], tk[1]), pk2(tk[2], tk[3]));
            T2[112 + d] = make_uint4(pk2(ta[0], ta[1]), pk2(ta[2], ta[3]),
                                     pk2(tb[0], tb[1]), pk2(tb[2], tb[3]));
        }
        return;
    }
    // ---------- GEMM path ----------
    __shared__ float xs[64 * KW];
    __shared__ float wt[64 * 128];
    __shared__ float s1[128], s2[128];
    const int b = blockIdx.x;

    if (t < 128) { s1[t] = 0.f; s2[t] = 0.f; }
    for (int idx = t; idx < 896; idx += 256) {
        int c = idx / 14, r = idx % 14;
        float4 v = *(const float4*)&x[c * 100352 + b * 56 + r * 4];
        *(float4*)&xs[c * 56 + r * 4] = v;
    }
    for (int idx = t; idx < 2048; idx += 256) {
        int o = idx >> 4, cq = idx & 15;
        float4 v = *(const float4*)&w[o * 64 + cq * 4];
        wt[(cq * 4 + 0) * 128 + o] = v.x;
        wt[(cq * 4 + 1) * 128 + o] = v.y;
        wt[(cq * 4 + 2) * 128 + o] = v.z;
        wt[(cq * 4 + 3) * 128 + o] = v.w;
    }
    __syncthreads();

    if (t < 224) {
        const int ob = t & 31, ib = t >> 5;
        v2f acc[4][4];
#pragma unroll
        for (int o = 0; o < 4; ++o)
#pragma unroll
            for (int ip = 0; ip < 4; ++ip) acc[o][ip] = (v2f)(0.f);
        for (int c = 0; c < 64; ++c) {
            float4 wv = *(const float4*)&wt[c * 128 + (ob << 2)];
            float4 x0 = *(const float4*)&xs[c * 56 + (ib << 3)];
            float4 x1 = *(const float4*)&xs[c * 56 + (ib << 3) + 4];
            v2f xp[4];
            xp[0] = (v2f){x0.x, x0.y}; xp[1] = (v2f){x0.z, x0.w};
            xp[2] = (v2f){x1.x, x1.y}; xp[3] = (v2f){x1.z, x1.w};
            v2f wd[4];
            wd[0] = (v2f)(wv.x); wd[1] = (v2f)(wv.y);
            wd[2] = (v2f)(wv.z); wd[3] = (v2f)(wv.w);
#pragma unroll
            for (int o = 0; o < 4; ++o)
#pragma unroll
                for (int ip = 0; ip < 4; ++ip)
                    acc[o][ip] += wd[o] * xp[ip];
        }
#pragma unroll
        for (int i = 0; i < 8; ++i) {
            float4 st;
            st.x = acc[0][i >> 1][i & 1];
            st.y = acc[1][i >> 1][i & 1];
            st.z = acc[2][i >> 1][i & 1];
            st.w = acc[3][i >> 1][i & 1];
            *(float4*)&qkv[b * 7168 + (ib * 8 + i) * 128 + ob * 4] = st;
        }
#pragma unroll
        for (int o = 0; o < 4; ++o) {
            float ps = 0.f, ps2 = 0.f;
#pragma unroll
            for (int ip = 0; ip < 4; ++ip) {
                ps  += acc[o][ip].x + acc[o][ip].y;
                ps2 += acc[o][ip].x * acc[o][ip].x + acc[o][ip].y * acc[o][ip].y;
            }
            atomicAdd(&s1[ob * 4 + o], ps);
            atomicAdd(&s2[ob * 4 + o], ps2);
        }
    }
    __syncthreads();
    if (t < 128) {
        float* dst = sums + (b & 7) * 256;
        atomicAdd(&dst[t], s1[t]);
        atomicAdd(&dst[128 + t], s2[t]);
    }
}

// ---------------- coef finalize (sums 8 slots) ----------------
__global__ void k_coef(const float* __restrict__ sums, const float* __restrict__ g,
                       const float* __restrict__ bb, float* __restrict__ coef,
                       int nch, float invM) {
    int o = blockIdx.x * blockDim.x + threadIdx.x;
    if (o < nch) {
        float a1 = 0.f, a2 = 0.f;
        for (int slot = 0; slot < 8; ++slot) {
            a1 += sums[slot * 2 * nch + o];
            a2 += sums[slot * 2 * nch + nch + o];
        }
        float mean = a1 * invM;
        float var  = fmaxf(a2 * invM - mean * mean, 0.f);
        float sc   = g[o] * rsqrtf(var + EPS);
        coef[o] = sc;
        coef[nch + o] = bb[o] - mean * sc;
    }
}

// ---------------- sim stats via Gram matrices (one wave per (b,g)) -----------
__global__ __launch_bounds__(256) void k_simstats(const float* __restrict__ qkv,
                                                  const float* __restrict__ qcoef,
                                                  const float* __restrict__ Rq,
                                                  const float* __restrict__ Rk,
                                                  const float* __restrict__ E2q,
                                                  const float* __restrict__ E2k,
                                                  float* __restrict__ ssum) {
    const int wid = threadIdx.x >> 6, lane = threadIdx.x & 63;
    const int unit = blockIdx.x * 4 + wid;
    const int b = unit >> 3, g = unit & 7;
    const int iL = lane < 56 ? lane : 55;
    const float valid = lane < 56 ? 1.f : 0.f;

    const float* row = qkv + b * 7168 + iL * 128 + g * 16;
    float4 q4 = *(const float4*)(row);
    float4 k4 = *(const float4*)(row + 4);
    const float4 aq = *(const float4*)&qcoef[g * 16];
    const float4 ak = *(const float4*)&qcoef[g * 16 + 4];
    const float4 cq = *(const float4*)&qcoef[QKV_CH + g * 16];
    const float4 ck = *(const float4*)&qcoef[QKV_CH + g * 16 + 4];
    float qv[4], kv[4];
    qv[0] = (q4.x * aq.x + cq.x) * valid;
    qv[1] = (q4.y * aq.y + cq.y) * valid;
    qv[2] = (q4.z * aq.z + cq.z) * valid;
    qv[3] = (q4.w * aq.w + cq.w) * valid;
    kv[0] = (k4.x * ak.x + ck.x) * valid;
    kv[1] = (k4.y * ak.y + ck.y) * valid;
    kv[2] = (k4.z * ak.z + ck.z) * valid;
    kv[3] = (k4.w * ak.w + ck.w) * valid;

    float4 rq = *(const float4*)&Rq[iL * 4];
    float4 rk = *(const float4*)&Rk[iL * 4];
    float e2q[10], e2k[10];
#pragma unroll
    for (int p = 0; p < 10; ++p) { e2q[p] = E2q[iL * 10 + p]; e2k[p] = E2k[iL * 10 + p]; }

    float red[32];
#pragma unroll
    for (int c = 0; c < 4; ++c) { red[c] = qv[c]; red[4 + c] = kv[c]; }
#pragma unroll
    for (int p = 0; p < 10; ++p) {
        red[8 + p]  = qv[PA[p]] * qv[PB[p]];
        red[18 + p] = kv[PA[p]] * kv[PB[p]];
    }
    {
        float rqa[4] = {rq.x, rq.y, rq.z, rq.w};
        float rka[4] = {rk.x, rk.y, rk.z, rk.w};
        float pq = 0.f, pk = 0.f, pq2 = 0.f, pk2 = 0.f;
#pragma unroll
        for (int c = 0; c < 4; ++c) { pq += qv[c] * rqa[c]; pk += kv[c] * rka[c]; }
#pragma unroll
        for (int p = 0; p < 10; ++p) {
            pq2 += PMf[p] * red[8 + p]  * e2q[p];
            pk2 += PMf[p] * red[18 + p] * e2k[p];
        }
        red[28] = pq; red[29] = pk; red[30] = pq2; red[31] = pk2;
    }
#pragma unroll
    for (int v = 0; v < 32; ++v) {
        float xv = red[v];
#pragma unroll
        for (int mk = 1; mk < 64; mk <<= 1) xv += __shfl_xor(xv, mk);
        red[v] = xv;
    }
    float sqk = 0.f, sqk2 = 0.f;
#pragma unroll
    for (int c = 0; c < 4; ++c) sqk += red[c] * red[4 + c];
#pragma unroll
    for (int p = 0; p < 10; ++p) sqk2 += PMf[p] * red[8 + p] * red[18 + p];
    if (lane == 0) {
        float* ss = ssum + (blockIdx.x & 7) * 48;
        atomicAdd(&ss[g], sqk);
        atomicAdd(&ss[8 + g], 0.1f * red[28]);
        atomicAdd(&ss[16 + g], 0.1f * red[29]);
        atomicAdd(&ss[SIM_CH + g], sqk2);
        atomicAdd(&ss[SIM_CH + 8 + g], 0.01f * red[30]);
        atomicAdd(&ss[SIM_CH + 16 + g], 0.01f * red[31]);
    }
}

// ---- attention: direct-j; k/v via readlane; bf16-packed tables (2 LDS/iter) --
__global__ __launch_bounds__(256) void k_attn(const float* __restrict__ qkv,
                                              const float* __restrict__ qcoef,
                                              const float* __restrict__ scoef,
                                              const uint4* __restrict__ T2,
                                              float* __restrict__ sv2,
                                              float* __restrict__ sve2,
                                              float* __restrict__ osums) {
    __shared__ uint4 Tqk[112];
    __shared__ uint4 Tvv[112];
    const int wid = threadIdx.x >> 6, lane = threadIdx.x & 63;
    const int unit = blockIdx.x * 4 + wid;
    const int b = unit >> 3, g = unit & 7;
    const int iL = lane < 56 ? lane : 55;

    for (int idx = threadIdx.x; idx < 224; idx += 256) {
        uint4 v = T2[idx];
        if (idx < 112) Tqk[idx] = v; else Tvv[idx - 112] = v;
    }

    const float* row = qkv + b * 7168 + iL * 128 + g * 16;
    float4 q4  = *(const float4*)(row);
    float4 k4  = *(const float4*)(row + 4);
    float4 va4 = *(const float4*)(row + 8);
    float4 vb4 = *(const float4*)(row + 12);
    const float4 a0 = *(const float4*)&qcoef[g * 16];
    const float4 a1 = *(const float4*)&qcoef[g * 16 + 4];
    const float4 a2 = *(const float4*)&qcoef[g * 16 + 8];
    const float4 a3 = *(const float4*)&qcoef[g * 16 + 12];
    const float4 c0 = *(const float4*)&qcoef[QKV_CH + g * 16];
    const float4 c1 = *(const float4*)&qcoef[QKV_CH + g * 16 + 4];
    const float4 c2 = *(const float4*)&qcoef[QKV_CH + g * 16 + 8];
    const float4 c3 = *(const float4*)&qcoef[QKV_CH + g * 16 + 12];
    float4 kh, vh, wh;
    kh.x = k4.x * a1.x + c1.x;  kh.y = k4.y * a1.y + c1.y;
    kh.z = k4.z * a1.z + c1.z;  kh.w = k4.w * a1.w + c1.w;
    vh.x = va4.x * a2.x + c2.x; vh.y = va4.y * a2.y + c2.y;
    vh.z = va4.z * a2.z + c2.z; vh.w = va4.w * a2.w + c2.w;
    wh.x = vb4.x * a3.x + c3.x; wh.y = vb4.y * a3.y + c3.y;
    wh.z = vb4.z * a3.z + c3.z; wh.w = vb4.w * a3.w + c3.w;
    float qh[4];
    qh[0] = q4.x * a0.x + c0.x;  qh[1] = q4.y * a0.y + c0.y;
    qh[2] = q4.z * a0.z + c0.z;  qh[3] = q4.w * a0.w + c0.w;
    __syncthreads();

    const float aqk = scoef[g];
    const float aqr = scoef[8 + g] * 0.1f;
    const float akr = scoef[16 + g] * 0.1f;
    const float cc  = scoef[SIM_CH + g] + scoef[SIM_CH + 8 + g] + scoef[SIM_CH + 16 + g];
    const float qa0 = qh[0] * aqk, qa1 = qh[1] * aqk, qa2 = qh[2] * aqk, qa3 = qh[3] * aqk;
    const float qr0 = qh[0] * aqr, qr1 = qh[1] * aqr, qr2 = qh[2] * aqr, qr3 = qh[3] * aqr;

    float l = 0.f;
    float sv[8], se[8];
#pragma unroll
    for (int c = 0; c < 8; ++c) { sv[c] = 0.f; se[c] = 0.f; }

#pragma unroll 4
    for (int j = 0; j < 56; ++j) {
        const int d = 55 + iL - j;
        const uint4 A = Tqk[d];
        const uint4 B = Tvv[d];
        const float k0 = rdlane(kh.x, j), k1 = rdlane(kh.y, j);
        const float k2 = rdlane(kh.z, j), k3 = rdlane(kh.w, j);
        const float v0 = rdlane(vh.x, j), v1 = rdlane(vh.y, j);
        const float v2 = rdlane(vh.z, j), v3 = rdlane(vh.w, j);
        const float w0 = rdlane(wh.x, j), w1 = rdlane(wh.y, j);
        const float w2 = rdlane(wh.z, j), w3 = rdlane(wh.w, j);
        float qr = qr0 * blo(A.x) + qr1 * bhi(A.x) + qr2 * blo(A.y) + qr3 * bhi(A.y);
        float kr = k0 * blo(A.z) + k1 * bhi(A.z) + k2 * blo(A.w) + k3 * bhi(A.w);
        float qk = cc + qa0 * k0 + qa1 * k1 + qa2 * k2 + qa3 * k3;
        float e = __expf(qk + qr + akr * kr);
        l += e;
        sv[0] += e * v0; sv[1] += e * v1; sv[2] += e * v2; sv[3] += e * v3;
        sv[4] += e * w0; sv[5] += e * w1; sv[6] += e * w2; sv[7] += e * w3;
        se[0] += e * blo(B.x); se[1] += e * bhi(B.x);
        se[2] += e * blo(B.y); se[3] += e * bhi(B.y);
        se[4] += e * blo(B.z); se[5] += e * bhi(B.z);
        se[6] += e * blo(B.w); se[7] += e * bhi(B.w);
    }
    const float inv = 1.f / l;
    const float inv1 = 0.1f * inv;
    float osv[8], ose[8];
#pragma unroll
    for (int c = 0; c < 8; ++c) { osv[c] = sv[c] * inv; ose[c] = se[c] * inv1; }

    if (lane < 56) {
        size_t base = ((size_t)(g * 8) * 1792 + b) * 56 + iL;
#pragma unroll
        for (int c = 0; c < 8; ++c) {
            sv2[base + (size_t)c * 100352]  = osv[c];
            sve2[base + (size_t)c * 100352] = ose[c];
        }
    }
    const float valid = lane < 56 ? 1.f : 0.f;
    float red[32];
#pragma unroll
    for (int c = 0; c < 8; ++c) {
        red[c]      = osv[c] * valid;
        red[8 + c]  = ose[c] * valid;
        red[16 + c] = osv[c] * osv[c] * valid;
        red[24 + c] = ose[c] * ose[c] * valid;
    }
#pragma unroll
    for (int v = 0; v < 32; ++v) {
        float xv = red[v];
#pragma unroll
        for (int mk = 1; mk < 64; mk <<= 1) xv += __shfl_xor(xv, mk);
        red[v] = xv;
    }
    if (lane == 0) {
        float* dst = osums + (blockIdx.x & 7) * 256;
#pragma unroll
        for (int c = 0; c < 8; ++c) {
            atomicAdd(&dst[g * 16 + 2 * c],           red[c]);
            atomicAdd(&dst[g * 16 + 2 * c + 1],       red[8 + c]);
            atomicAdd(&dst[128 + g * 16 + 2 * c],     red[16 + c]);
            atomicAdd(&dst[128 + g * 16 + 2 * c + 1], red[24 + c]);
        }
    }
}

// ---------------- out: streaming affine combine, fully coalesced --------------
__global__ __launch_bounds__(256) void k_out(const float* __restrict__ sv2,
                                             const float* __restrict__ sve2,
                                             const float* __restrict__ ocoef,
                                             float* __restrict__ out) {
    int e4 = blockIdx.x * 256 + threadIdx.x;
    int i0 = e4 * 4;
    int oc = i0 / 100352;
    int o0 = 2 * oc;
    float A = ocoef[o0], B = ocoef[o0 + 1];
    float C = ocoef[QKV_CH + o0] + ocoef[QKV_CH + o0 + 1];
    float4 v0 = *(const float4*)&sv2[i0];
    float4 v1 = *(const float4*)&sve2[i0];
    float4 r;
    r.x = A * v0.x + B * v1.x + C;
    r.y = A * v0.y + B * v1.y + C;
    r.z = A * v0.z + B * v1.z + C;
    r.w = A * v0.w + B * v1.w + C;
    *(float4*)&out[i0] = r;
}

extern "C" void kernel_launch(void* const* d_in, const int* in_sizes, int n_in,
                              void* d_out, int out_size, void* d_ws, size_t ws_size,
                              hipStream_t stream) {
    const float* x     = (const float*)d_in[0];
    const float* wqkv  = (const float*)d_in[1];
    const float* rel   = (const float*)d_in[2];
    const float* g_qkv = (const float*)d_in[3];
    const float* b_qkv = (const float*)d_in[4];
    const float* g_sim = (const float*)d_in[5];
    const float* b_sim = (const float*)d_in[6];
    const float* g_out = (const float*)d_in[7];
    const float* b_out = (const float*)d_in[8];
    float* out = (float*)d_out;
    float* ws = (float*)d_ws;

    float* qkv_raw  = ws;                       // [b][i][o]  12,845,056
    float* sv2      = ws + 12845056;            // out-layout  6,422,528
    float* sve2     = ws + 19267584;            // out-layout  6,422,528
    float* stats    = ws + 25690112;
    float* qkv_sums = stats;                    // 8 x 256
    float* sim_sums = stats + 2048;             // 8 x 48
    float* out_sums = stats + 2432;             // 8 x 256
    float* qkv_coef = stats + 4480;             // 256
    float* sim_coef = stats + 4736;             // 48
    float* out_coef = stats + 4784;             // 256
    float* tabs     = stats + 5040;             // Rq/Rk/E2q/E2k (1568) + T2 (896)
    float* Rq   = tabs;
    float* Rk   = tabs + 224;
    float* E2q  = tabs + 448;
    float* E2k  = tabs + 1008;
    uint4* T2   = (uint4*)(tabs + 1568);

    hipMemsetAsync(stats, 0, 4480 * sizeof(float), stream);

    k_qkv<<<NB + 8, 256, 0, stream>>>(x, wqkv, rel, qkv_raw, qkv_sums, tabs);
    k_coef<<<1, 128, 0, stream>>>(qkv_sums, g_qkv, b_qkv, qkv_coef, QKV_CH,
                                  1.0f / 100352.0f);
    k_simstats<<<3584, 256, 0, stream>>>(qkv_raw, qkv_coef, Rq, Rk, E2q, E2k,
                                         sim_sums);
    k_coef<<<1, 128, 0, stream>>>(sim_sums, g_sim, b_sim, sim_coef, SIM_CH,
                                  1.0f / 5619712.0f);
    k_attn<<<3584, 256, 0, stream>>>(qkv_raw, qkv_coef, sim_coef, T2,
                                     sv2, sve2, out_sums);
    k_coef<<<1, 128, 0, stream>>>(out_sums, g_out, b_out, out_coef, QKV_CH,
                                  1.0f / 100352.0f);
    k_out<<<6272, 256, 0, stream>>>(sv2, sve2, out_coef, out);
}